// Round 1
// baseline (1967.181 us; speedup 1.0000x reference)
//
#include <hip/hip_runtime.h>
#include <hip/hip_bf16.h>
#include <math.h>

// Problem constants
// B=4, N=1024, D=768, H=12, HD=64, M=100, FF=3072
// Attention is EXACTLY banded with radius 99 (rel-pos mask adds -1e8 outside,
// exp underflows to 0 in fp32), so we only compute the 199-wide band.

#define BM 128
#define BN 128
#define BK 8

// MODE: 0 = scatter to q/k/v (B,H,N,HD), 1 = +bias+resid -> C, 2 = +bias, exact GELU -> C
template<int MODE>
__global__ void __launch_bounds__(256)
gemm_nt_kernel(const float* __restrict__ A, const float* __restrict__ W,
               const float* __restrict__ bias, const float* __restrict__ resid,
               float* __restrict__ C, int M, int N, int K,
               float* __restrict__ qb, float* __restrict__ kb, float* __restrict__ vb)
{
    // C[row,col] = sum_k A[row,k] * W[col,k]  (both row-major, K contiguous)
    __shared__ float As[BK][BM];
    __shared__ float Bs[BK][BN];
    const int tid = threadIdx.x;
    const int tx = tid & 15;
    const int ty = tid >> 4;
    const int row0 = blockIdx.y * BM;
    const int col0 = blockIdx.x * BN;
    const int lr = tid >> 1;          // 0..127
    const int lk = (tid & 1) * 4;     // 0 or 4

    float acc[8][8];
#pragma unroll
    for (int i = 0; i < 8; ++i)
#pragma unroll
        for (int j = 0; j < 8; ++j) acc[i][j] = 0.f;

    const float* Aldg = A + (size_t)(row0 + lr) * K + lk;
    const float* Wldg = W + (size_t)(col0 + lr) * K + lk;

    for (int k0 = 0; k0 < K; k0 += BK) {
        const float4 av = *(const float4*)(Aldg + k0);
        const float4 bv = *(const float4*)(Wldg + k0);
        As[lk + 0][lr] = av.x; As[lk + 1][lr] = av.y; As[lk + 2][lr] = av.z; As[lk + 3][lr] = av.w;
        Bs[lk + 0][lr] = bv.x; Bs[lk + 1][lr] = bv.y; Bs[lk + 2][lr] = bv.z; Bs[lk + 3][lr] = bv.w;
        __syncthreads();
#pragma unroll
        for (int kk = 0; kk < BK; ++kk) {
            const float4 a0 = *(const float4*)&As[kk][ty * 8];
            const float4 a1 = *(const float4*)&As[kk][ty * 8 + 4];
            const float4 b0 = *(const float4*)&Bs[kk][tx * 8];
            const float4 b1 = *(const float4*)&Bs[kk][tx * 8 + 4];
            const float a[8] = {a0.x, a0.y, a0.z, a0.w, a1.x, a1.y, a1.z, a1.w};
            const float b[8] = {b0.x, b0.y, b0.z, b0.w, b1.x, b1.y, b1.z, b1.w};
#pragma unroll
            for (int i = 0; i < 8; ++i)
#pragma unroll
                for (int j = 0; j < 8; ++j)
                    acc[i][j] = fmaf(a[i], b[j], acc[i][j]);
        }
        __syncthreads();
    }

#pragma unroll
    for (int i = 0; i < 8; ++i) {
        const int row = row0 + ty * 8 + i;
#pragma unroll
        for (int j = 0; j < 8; ++j) {
            const int col = col0 + tx * 8 + j;
            float v = acc[i][j] + bias[col];
            if (MODE == 0) {
                const int which = col / 768;
                const int rem = col - which * 768;
                const int h = rem >> 6;
                const int d = rem & 63;
                const int b = row >> 10;
                const int n = row & 1023;
                float* dst = (which == 0) ? qb : (which == 1) ? kb : vb;
                dst[((size_t)(b * 12 + h) * 1024 + n) * 64 + d] = v;
            } else if (MODE == 1) {
                const size_t idx = (size_t)row * N + col;
                C[idx] = v + resid[idx];
            } else {
                const size_t idx = (size_t)row * N + col;
                C[idx] = 0.5f * v * (1.0f + erff(v * 0.70710678118654752f));
            }
        }
    }
}

// Banded attention: one block per (b,h,i). Band j in [i-99, i+99] ∩ [0,1024).
// logits = 0.125 * q[b,h,i]·k[b,h,j] + qpos·emb[h, j-i+99]
// qpos = q[b2,h,n2] with t = i*4+b, b2 = t>>10, n2 = t&1023 (fairseq flat-reshape scramble).
__global__ void __launch_bounds__(256)
attn_kernel(const float* __restrict__ qb, const float* __restrict__ kb,
            const float* __restrict__ vb, const float* __restrict__ emb,
            float* __restrict__ ctx)
{
    const int i = blockIdx.x;   // query position
    const int h = blockIdx.y;
    const int b = blockIdx.z;
    const int t = threadIdx.x;

    __shared__ float qv[64];
    __shared__ float qp[64];
    __shared__ float rb[256];
    __shared__ float pb[256];

    const size_t bh = (size_t)(b * 12 + h) * 1024;

    if (t < 64) {
        qv[t] = qb[(bh + i) * 64 + t];
    } else if (t < 128) {
        const int tt = i * 4 + b;
        const int b2 = tt >> 10;
        const int n2 = tt & 1023;
        qp[t - 64] = qb[((size_t)(b2 * 12 + h) * 1024 + n2) * 64 + (t - 64)];
    }
    __syncthreads();

    const int jlo = (i > 99) ? (i - 99) : 0;
    const int jhi = (i + 99 < 1023) ? (i + 99) : 1023;
    const int cnt = jhi - jlo + 1;   // <= 199

    float s = -1e30f;
    float p = 0.f;
    if (t < cnt) {
        const int j = jlo + t;
        const float* kr = kb + (bh + j) * 64;
        const float* er = emb + (size_t)(h * 199 + (j - i + 99)) * 64;
        float s1 = 0.f, s2 = 0.f;
#pragma unroll
        for (int d = 0; d < 64; ++d) {
            s1 = fmaf(qv[d], kr[d], s1);
            s2 = fmaf(qp[d], er[d], s2);
        }
        s = s1 * 0.125f + s2;
    }
    rb[t] = s;
    __syncthreads();
#pragma unroll
    for (int off = 128; off > 0; off >>= 1) {
        if (t < off) rb[t] = fmaxf(rb[t], rb[t + off]);
        __syncthreads();
    }
    const float mx = rb[0];
    __syncthreads();
    if (t < cnt) p = expf(s - mx);
    rb[t] = p;
    __syncthreads();
#pragma unroll
    for (int off = 128; off > 0; off >>= 1) {
        if (t < off) rb[t] += rb[t + off];
        __syncthreads();
    }
    const float denom = rb[0];
    __syncthreads();
    pb[t] = p / denom;
    __syncthreads();

    // PV: 4 j-groups x 64 d-lanes (coalesced v reads)
    const int d = t & 63;
    const int g = t >> 6;
    float acc = 0.f;
    const float* vbase = vb + (bh + jlo) * 64 + d;
    for (int jj = g; jj < cnt; jj += 4)
        acc = fmaf(pb[jj], vbase[(size_t)jj * 64], acc);
    rb[t] = acc;
    __syncthreads();
    if (t < 64) {
        const float o = rb[t] + rb[t + 64] + rb[t + 128] + rb[t + 192];
        ctx[((size_t)(b * 1024 + i)) * 768 + h * 64 + t] = o;
    }
}

// In-place LayerNorm over rows of (4096, 768). One block (256 thr) per row.
__global__ void __launch_bounds__(256)
layernorm_kernel(float* __restrict__ x, const float* __restrict__ g, const float* __restrict__ bta)
{
    const int row = blockIdx.x;
    float* xr = x + (size_t)row * 768;
    const int t = threadIdx.x;
    const float v0 = xr[t], v1 = xr[t + 256], v2 = xr[t + 512];
    __shared__ float red[4];
    float s = v0 + v1 + v2;
#pragma unroll
    for (int off = 32; off > 0; off >>= 1) s += __shfl_down(s, off);
    if ((t & 63) == 0) red[t >> 6] = s;
    __syncthreads();
    const float mu = (red[0] + red[1] + red[2] + red[3]) * (1.0f / 768.0f);
    __syncthreads();
    const float d0 = v0 - mu, d1 = v1 - mu, d2 = v2 - mu;
    float q = d0 * d0 + d1 * d1 + d2 * d2;
#pragma unroll
    for (int off = 32; off > 0; off >>= 1) q += __shfl_down(q, off);
    if ((t & 63) == 0) red[t >> 6] = q;
    __syncthreads();
    const float var = (red[0] + red[1] + red[2] + red[3]) * (1.0f / 768.0f);
    const float rstd = rsqrtf(var + 1e-5f);
    xr[t]       = d0 * rstd * g[t]       + bta[t];
    xr[t + 256] = d1 * rstd * g[t + 256] + bta[t + 256];
    xr[t + 512] = d2 * rstd * g[t + 512] + bta[t + 512];
}

extern "C" void kernel_launch(void* const* d_in, const int* in_sizes, int n_in,
                              void* d_out, int out_size, void* d_ws, size_t ws_size,
                              hipStream_t stream)
{
    const float* src    = (const float*)d_in[0];
    const float* qkv_w  = (const float*)d_in[1];
    const float* qkv_b  = (const float*)d_in[2];
    const float* rel    = (const float*)d_in[3];
    const float* proj_w = (const float*)d_in[4];
    const float* proj_b = (const float*)d_in[5];
    const float* ln1_g  = (const float*)d_in[6];
    const float* ln1_b  = (const float*)d_in[7];
    const float* fc1_w  = (const float*)d_in[8];
    const float* fc1_b  = (const float*)d_in[9];
    const float* fc2_w  = (const float*)d_in[10];
    const float* fc2_b  = (const float*)d_in[11];
    const float* ln2_g  = (const float*)d_in[12];
    const float* ln2_b  = (const float*)d_in[13];
    float* out = (float*)d_out;
    float* ws  = (float*)d_ws;

    const size_t SEG = 3145728;   // 4*1024*768 elements
    float* qb   = ws;             // (B,H,N,HD)
    float* kb   = qb + SEG;
    float* vb   = kb + SEG;
    float* ctx  = vb + SEG;       // (B,N,D)
    float* xbuf = ctx + SEG;      // (B,N,D) post-LN1 x
    float* h1   = ws;             // (4096,3072) aliases qb..ctx (exactly 4*SEG, dead by then)

    // 1) QKV GEMM: (4096x768) @ (2304x768)^T -> scatter q/k/v
    gemm_nt_kernel<0><<<dim3(2304 / BN, 4096 / BM), 256, 0, stream>>>(
        src, qkv_w, qkv_b, nullptr, nullptr, 4096, 2304, 768, qb, kb, vb);

    // 2) Banded attention -> ctx (B,N,D)
    attn_kernel<<<dim3(1024, 12, 4), 256, 0, stream>>>(qb, kb, vb, rel, ctx);

    // 3) proj GEMM + bias + residual(src) -> xbuf
    gemm_nt_kernel<1><<<dim3(768 / BN, 4096 / BM), 256, 0, stream>>>(
        ctx, proj_w, proj_b, src, xbuf, 4096, 768, 768, nullptr, nullptr, nullptr);

    // 4) LN1 in place on xbuf
    layernorm_kernel<<<4096, 256, 0, stream>>>(xbuf, ln1_g, ln1_b);

    // 5) fc1 GEMM + bias + exact GELU -> h1
    gemm_nt_kernel<2><<<dim3(3072 / BN, 4096 / BM), 256, 0, stream>>>(
        xbuf, fc1_w, fc1_b, nullptr, h1, 4096, 3072, 768, nullptr, nullptr, nullptr);

    // 6) fc2 GEMM + bias + residual(xbuf) -> out
    gemm_nt_kernel<1><<<dim3(768 / BN, 4096 / BM), 256, 0, stream>>>(
        h1, fc2_w, fc2_b, xbuf, out, 4096, 768, 3072, nullptr, nullptr, nullptr);

    // 7) LN2 in place on out
    layernorm_kernel<<<4096, 256, 0, stream>>>(out, ln2_g, ln2_b);
}

// Round 3
// 480.568 us; speedup vs baseline: 4.0934x; 4.0934x over previous
//
#include <hip/hip_runtime.h>
#include <hip/hip_bf16.h>
#include <math.h>

// B=4, N=1024, D=768, H=12, HD=64, M=100, FF=3072
// Attention is EXACTLY banded, radius 99 (rel-pos mask -1e8 outside, exp->0).
// Pipeline (all bf16 MFMA GEMMs, fp32 residual/LN spine):
//  converts -> QKV gemm (scatter q, kT, v bf16) -> attn (wave/query) -> ctx bf16
//  -> proj gemm (+bias+src resid -> xbuf f32) -> LN1 (f32 + bf16 out)
//  -> fc1 gemm (+bias, GELU -> h1 bf16) -> fc2 gemm (+bias + xbuf resid -> out f32)
//  -> LN2 in place.

typedef __attribute__((ext_vector_type(8))) short bf16x8;
typedef __attribute__((ext_vector_type(4))) float f32x4;

#define GLDS16(g, l) __builtin_amdgcn_global_load_lds( \
    (const __attribute__((address_space(1))) void*)(g), \
    (__attribute__((address_space(3))) void*)(l), 16, 0, 0)

__device__ __forceinline__ unsigned short f2bu(float x) {
    union { __hip_bfloat16 h; unsigned short u; } c;
    c.h = __float2bfloat16(x);
    return c.u;
}
__device__ __forceinline__ float bu2f(unsigned short u) {
    union { __hip_bfloat16 h; unsigned short u; } c;
    c.u = u;
    return __bfloat162float(c.h);
}

// ---------------- fp32 -> bf16 convert (vectorized) ----------------
__global__ void __launch_bounds__(256)
f2b4_kernel(const float* __restrict__ in, unsigned short* __restrict__ out, int n4)
{
    const int idx = blockIdx.x * 256 + threadIdx.x;
    if (idx < n4) {
        const float4 v = ((const float4*)in)[idx];
        ushort4 o;
        o.x = f2bu(v.x); o.y = f2bu(v.y); o.z = f2bu(v.z); o.w = f2bu(v.w);
        ((ushort4*)out)[idx] = o;
    }
}

// emb (H,199,HD,1) fp32 -> embT (H,HD,199) bf16
__global__ void __launch_bounds__(256)
embt_kernel(const float* __restrict__ rel, unsigned short* __restrict__ embT)
{
    const int idx = blockIdx.x * 256 + threadIdx.x;   // (h*199+r)*64+d, d fastest
    if (idx < 12 * 199 * 64) {
        const int d = idx & 63;
        const int hr = idx >> 6;
        const int h = hr / 199;
        const int r = hr - h * 199;
        embT[((size_t)h * 64 + d) * 199 + r] = f2bu(rel[idx]);
    }
}

// ---------------- bf16 MFMA GEMM, NT: C[r,c] = sum_k A[r,k]*W[c,k] ----------------
// 128x128 tile, 256 thr = 4 waves (2x2), each wave 64x64 = 4x4 frags of 16x16x32.
// MODE 0: +bias, scatter to q (b,h,n,d) / kT (b,h,d,n) / v (b,h,n,d), bf16
// MODE 1: +bias +resid(f32) -> Cf (f32)
// MODE 2: +bias, exact GELU -> Cb (bf16)
template<int MODE>
__global__ void __launch_bounds__(256)
gemm_bf16_kernel(const unsigned short* __restrict__ A, const unsigned short* __restrict__ W,
                 const float* __restrict__ bias, const float* __restrict__ resid,
                 float* __restrict__ Cf, unsigned short* __restrict__ Cb,
                 int Ndim, int K,
                 unsigned short* __restrict__ qb, unsigned short* __restrict__ kTb,
                 unsigned short* __restrict__ vb)
{
    __shared__ short As[128 * 64];
    __shared__ short Bs[128 * 64];
    const int tid = threadIdx.x;
    const int l = tid & 63;
    const int w = tid >> 6;
    const int wr = w >> 1, wc = w & 1;
    const int row0 = blockIdx.y * 128;
    const int col0 = blockIdx.x * 128;

    f32x4 acc[4][4];
#pragma unroll
    for (int m = 0; m < 4; ++m)
#pragma unroll
        for (int n = 0; n < 4; ++n) acc[m][n] = (f32x4){0.f, 0.f, 0.f, 0.f};

    const int lrow = l >> 3;          // 0..7 row within 8-row chunk
    const int lcol = (l & 7) * 8;     // element col within 64

    for (int k0 = 0; k0 < K; k0 += 64) {
        __syncthreads();   // prev compute's LDS reads drained (compiler lgkmcnt)
#pragma unroll
        for (int it = 0; it < 4; ++it) {
            const int c = w * 4 + it;                   // chunk 0..15 = rows c*8..c*8+7
            const unsigned short* ga = A + (size_t)(row0 + c * 8 + lrow) * K + k0 + lcol;
            const unsigned short* gb = W + (size_t)(col0 + c * 8 + lrow) * K + k0 + lcol;
            GLDS16(ga, As + c * 512);                   // wave-uniform LDS base + lane*16
            GLDS16(gb, Bs + c * 512);
        }
        __syncthreads();   // compiler emits vmcnt(0) before barrier -> tiles ready
#pragma unroll
        for (int kk = 0; kk < 2; ++kk) {
            bf16x8 af[4], bfr[4];
#pragma unroll
            for (int m = 0; m < 4; ++m)
                af[m] = *(const bf16x8*)(As + (wr * 64 + m * 16 + (l & 15)) * 64 + kk * 32 + (l >> 4) * 8);
#pragma unroll
            for (int n = 0; n < 4; ++n)
                bfr[n] = *(const bf16x8*)(Bs + (wc * 64 + n * 16 + (l & 15)) * 64 + kk * 32 + (l >> 4) * 8);
#pragma unroll
            for (int m = 0; m < 4; ++m)
#pragma unroll
                for (int n = 0; n < 4; ++n)
                    acc[m][n] = __builtin_amdgcn_mfma_f32_16x16x32_bf16(af[m], bfr[n], acc[m][n], 0, 0, 0);
        }
    }

    // Epilogue. D mapping (m89-verified): col = lane&15, row = (lane>>4)*4 + reg
#pragma unroll
    for (int m = 0; m < 4; ++m) {
#pragma unroll
        for (int n = 0; n < 4; ++n) {
#pragma unroll
            for (int r = 0; r < 4; ++r) {
                const int row = row0 + wr * 64 + m * 16 + (l >> 4) * 4 + r;
                const int col = col0 + wc * 64 + n * 16 + (l & 15);
                float v = acc[m][n][r] + bias[col];
                if (MODE == 0) {
                    const int which = col / 768;
                    const int rem = col - which * 768;
                    const int h = rem >> 6, d = rem & 63;
                    const int b = row >> 10, nn = row & 1023;
                    if (which == 0)
                        qb[((size_t)(b * 12 + h) * 1024 + nn) * 64 + d] = f2bu(v);
                    else if (which == 1)
                        kTb[((size_t)(b * 12 + h) * 64 + d) * 1024 + nn] = f2bu(v);
                    else
                        vb[((size_t)(b * 12 + h) * 1024 + nn) * 64 + d] = f2bu(v);
                } else if (MODE == 1) {
                    const size_t idx = (size_t)row * Ndim + col;
                    Cf[idx] = v + resid[idx];
                } else {
                    const size_t idx = (size_t)row * Ndim + col;
                    const float g = 0.5f * v * (1.0f + erff(v * 0.70710678118654752f));
                    Cb[idx] = f2bu(g);
                }
            }
        }
    }
}

// ---------------- banded attention, one wave per query ----------------
// logits = 0.125*q.k + qpos.emb[j-i+99]; qpos row from fairseq flat-reshape scramble.
__global__ void __launch_bounds__(256)
attn_kernel(const unsigned short* __restrict__ qb, const unsigned short* __restrict__ kT,
            const unsigned short* __restrict__ vb, const unsigned short* __restrict__ embT,
            unsigned short* __restrict__ ctx)
{
    const int i0 = blockIdx.x * 4;
    const int h = blockIdx.y;
    const int b = blockIdx.z;
    const int tid = threadIdx.x;
    const int w = tid >> 6;
    const int lane = tid & 63;

    __shared__ float q_s[4][64];
    __shared__ float qp_s[4][64];
    __shared__ float p_s[4][256];

    {
        const int w2 = tid >> 6, d = tid & 63;
        const int iq = i0 + w2;
        q_s[w2][d] = bu2f(qb[((size_t)(b * 12 + h) * 1024 + iq) * 64 + d]);
        const int tt = iq * 4 + b;
        const int b2 = tt >> 10, n2 = tt & 1023;
        qp_s[w2][d] = bu2f(qb[((size_t)(b2 * 12 + h) * 1024 + n2) * 64 + d]);
    }
    __syncthreads();

    const int i = i0 + w;
    const int jlo = (i > 99) ? i - 99 : 0;
    const int jhi = (i < 924) ? i + 99 : 1023;
    const int cnt = jhi - jlo + 1;   // 100..199
    const int r0 = jlo - i + 99;     // >= 0

    const unsigned short* kbase = kT + (size_t)(b * 12 + h) * 64 * 1024;  // [d][n]
    const unsigned short* ebase = embT + (size_t)h * 64 * 199;            // [d][r]

    int offc[4];
    bool val[4];
#pragma unroll
    for (int s = 0; s < 4; ++s) {
        const int off = lane + 64 * s;
        val[s] = off < cnt;
        offc[s] = val[s] ? off : (cnt - 1);
    }

    float sq[4] = {0.f, 0.f, 0.f, 0.f}, sp[4] = {0.f, 0.f, 0.f, 0.f};
    for (int d = 0; d < 64; ++d) {
        const float qv = q_s[w][d];
        const float qp = qp_s[w][d];
        const unsigned short* krow = kbase + d * 1024 + jlo;
        const unsigned short* erow = ebase + d * 199 + r0;
#pragma unroll
        for (int s = 0; s < 4; ++s) {
            sq[s] = fmaf(qv, bu2f(krow[offc[s]]), sq[s]);
            sp[s] = fmaf(qp, bu2f(erow[offc[s]]), sp[s]);
        }
    }

    float sv[4];
#pragma unroll
    for (int s = 0; s < 4; ++s)
        sv[s] = val[s] ? (0.125f * sq[s] + sp[s]) : -INFINITY;

    float mx = fmaxf(fmaxf(sv[0], sv[1]), fmaxf(sv[2], sv[3]));
#pragma unroll
    for (int o = 1; o < 64; o <<= 1) mx = fmaxf(mx, __shfl_xor(mx, o, 64));

    float pr[4], sum = 0.f;
#pragma unroll
    for (int s = 0; s < 4; ++s) {
        pr[s] = val[s] ? expf(sv[s] - mx) : 0.f;
        sum += pr[s];
    }
#pragma unroll
    for (int o = 1; o < 64; o <<= 1) sum += __shfl_xor(sum, o, 64);
    const float inv = 1.0f / sum;
#pragma unroll
    for (int s = 0; s < 4; ++s) p_s[w][lane + 64 * s] = pr[s] * inv;
    __syncthreads();

    // PV: lane = d, coalesced v reads, p broadcast from LDS
    float acc = 0.f;
    const unsigned short* vrow = vb + ((size_t)(b * 12 + h) * 1024 + jlo) * 64 + lane;
#pragma unroll 4
    for (int jj = 0; jj < cnt; ++jj)
        acc = fmaf(p_s[w][jj], bu2f(vrow[(size_t)jj * 64]), acc);

    ctx[((size_t)(b * 1024) + i) * 768 + h * 64 + lane] = f2bu(acc);
}

// ---------------- in-place LayerNorm rows of (4096,768), optional bf16 copy ----------------
__global__ void __launch_bounds__(256)
layernorm_kernel(float* __restrict__ x, const float* __restrict__ g, const float* __restrict__ bta,
                 unsigned short* __restrict__ xb)
{
    const int row = blockIdx.x;
    float* xr = x + (size_t)row * 768;
    const int t = threadIdx.x;
    const float v0 = xr[t], v1 = xr[t + 256], v2 = xr[t + 512];
    __shared__ float red[4];
    float s = v0 + v1 + v2;
#pragma unroll
    for (int off = 32; off > 0; off >>= 1) s += __shfl_down(s, off);
    if ((t & 63) == 0) red[t >> 6] = s;
    __syncthreads();
    const float mu = (red[0] + red[1] + red[2] + red[3]) * (1.0f / 768.0f);
    __syncthreads();
    const float d0 = v0 - mu, d1 = v1 - mu, d2 = v2 - mu;
    float q = d0 * d0 + d1 * d1 + d2 * d2;
#pragma unroll
    for (int off = 32; off > 0; off >>= 1) q += __shfl_down(q, off);
    if ((t & 63) == 0) red[t >> 6] = q;
    __syncthreads();
    const float var = (red[0] + red[1] + red[2] + red[3]) * (1.0f / 768.0f);
    const float rstd = rsqrtf(var + 1e-5f);
    const float y0 = d0 * rstd * g[t] + bta[t];
    const float y1 = d1 * rstd * g[t + 256] + bta[t + 256];
    const float y2 = d2 * rstd * g[t + 512] + bta[t + 512];
    xr[t] = y0; xr[t + 256] = y1; xr[t + 512] = y2;
    if (xb) {
        unsigned short* xbr = xb + (size_t)row * 768;
        xbr[t] = f2bu(y0); xbr[t + 256] = f2bu(y1); xbr[t + 512] = f2bu(y2);
    }
}

extern "C" void kernel_launch(void* const* d_in, const int* in_sizes, int n_in,
                              void* d_out, int out_size, void* d_ws, size_t ws_size,
                              hipStream_t stream)
{
    const float* src    = (const float*)d_in[0];
    const float* qkv_w  = (const float*)d_in[1];
    const float* qkv_b  = (const float*)d_in[2];
    const float* rel    = (const float*)d_in[3];
    const float* proj_w = (const float*)d_in[4];
    const float* proj_b = (const float*)d_in[5];
    const float* ln1_g  = (const float*)d_in[6];
    const float* ln1_b  = (const float*)d_in[7];
    const float* fc1_w  = (const float*)d_in[8];
    const float* fc1_b  = (const float*)d_in[9];
    const float* fc2_w  = (const float*)d_in[10];
    const float* fc2_b  = (const float*)d_in[11];
    const float* ln2_g  = (const float*)d_in[12];
    const float* ln2_b  = (const float*)d_in[13];
    float* out = (float*)d_out;
    char* W = (char*)d_ws;

    // Workspace layout (bytes). Lifetimes carefully overlapped; peak 53.5 MB.
    unsigned short* kT_b    = (unsigned short*)(W + 0);          // 6291456 B, dies after attn
    unsigned short* v_b     = (unsigned short*)(W + 6291456);    // 6291456 B, dies after attn
    unsigned short* q_b     = (unsigned short*)(W + 12582912);   // 6291456 B, dies after attn
    float*          xbuf    = (float*)(W + 0);                   // 12582912 B, from proj on
    unsigned short* xbuf_b  = (unsigned short*)(W + 12582912);   // 6291456 B, from LN1 on
    char* R2 = W + 18874368;
    unsigned short* src_b   = (unsigned short*)(R2 + 0);         // 6291456 B, dies after QKV
    unsigned short* qkvw_b  = (unsigned short*)(R2 + 6291456);   // 3538944 B, dies after QKV
    unsigned short* projw_b = (unsigned short*)(R2 + 9830400);   // 1179648 B, dies after proj
    unsigned short* embT_b  = (unsigned short*)(R2 + 11010048);  // 305664 B, dies after attn
    unsigned short* ctx_b   = (unsigned short*)(R2 + 11315712);  // 6291456 B, dies after proj
    unsigned short* h1_b    = (unsigned short*)(R2 + 0);         // 25165824 B, from fc1 on
    unsigned short* fc1w_b  = (unsigned short*)(W + 44040192);   // 4718592 B
    unsigned short* fc2w_b  = (unsigned short*)(W + 48758784);   // 4718592 B

    // 0) converts
    f2b4_kernel<<<3145728 / 4 / 256, 256, 0, stream>>>(src, src_b, 3145728 / 4);
    f2b4_kernel<<<1769472 / 4 / 256, 256, 0, stream>>>(qkv_w, qkvw_b, 1769472 / 4);
    f2b4_kernel<<<589824 / 4 / 256, 256, 0, stream>>>(proj_w, projw_b, 589824 / 4);
    f2b4_kernel<<<2359296 / 4 / 256, 256, 0, stream>>>(fc1_w, fc1w_b, 2359296 / 4);
    f2b4_kernel<<<2359296 / 4 / 256, 256, 0, stream>>>(fc2_w, fc2w_b, 2359296 / 4);
    embt_kernel<<<(12 * 199 * 64 + 255) / 256, 256, 0, stream>>>(rel, embT_b);

    // 1) QKV: (4096x768)@(2304x768)^T, scatter q/kT/v bf16
    gemm_bf16_kernel<0><<<dim3(2304 / 128, 4096 / 128), 256, 0, stream>>>(
        src_b, qkvw_b, qkv_b, nullptr, nullptr, nullptr, 2304, 768, q_b, kT_b, v_b);

    // 2) banded attention -> ctx bf16
    attn_kernel<<<dim3(256, 12, 4), 256, 0, stream>>>(q_b, kT_b, v_b, embT_b, ctx_b);

    // 3) proj + bias + src residual -> xbuf f32
    gemm_bf16_kernel<1><<<dim3(768 / 128, 4096 / 128), 256, 0, stream>>>(
        ctx_b, projw_b, proj_b, src, xbuf, nullptr, 768, 768, nullptr, nullptr, nullptr);

    // 4) LN1 in place + bf16 copy
    layernorm_kernel<<<4096, 256, 0, stream>>>(xbuf, ln1_g, ln1_b, xbuf_b);

    // 5) fc1 + bias + GELU -> h1 bf16
    gemm_bf16_kernel<2><<<dim3(3072 / 128, 4096 / 128), 256, 0, stream>>>(
        xbuf_b, fc1w_b, fc1_b, nullptr, nullptr, h1_b, 3072, 768, nullptr, nullptr, nullptr);

    // 6) fc2 + bias + xbuf residual -> out f32
    gemm_bf16_kernel<1><<<dim3(768 / 128, 4096 / 128), 256, 0, stream>>>(
        h1_b, fc2w_b, fc2_b, xbuf, out, nullptr, 768, 3072, nullptr, nullptr, nullptr);

    // 7) LN2 in place
    layernorm_kernel<<<4096, 256, 0, stream>>>(out, ln2_g, ln2_b, nullptr);
}

// Round 5
// 260.660 us; speedup vs baseline: 7.5469x; 1.8437x over previous
//
#include <hip/hip_runtime.h>
#include <hip/hip_bf16.h>
#include <math.h>

// B=4, N=1024, D=768, H=12, HD=64, M=100, FF=3072
// Attention is EXACTLY banded, radius 99 (rel-pos mask -1e8 outside, exp->0 in f32).
// Round 4: attention moved to MFMA (QK^T, Qpos·Emb^T, PV all matrix-core),
// skew combine via LDS, wave-parallel softmax in registers.

typedef __attribute__((ext_vector_type(8))) short bf16x8;
typedef __attribute__((ext_vector_type(4))) float f32x4;

#define GLDS16(g, l) __builtin_amdgcn_global_load_lds( \
    (const __attribute__((address_space(1))) void*)(g), \
    (__attribute__((address_space(3))) void*)(l), 16, 0, 0)

__device__ __forceinline__ unsigned short f2bu(float x) {
    union { __hip_bfloat16 h; unsigned short u; } c;
    c.h = __float2bfloat16(x);
    return c.u;
}
__device__ __forceinline__ float bu2f(unsigned short u) {
    union { __hip_bfloat16 h; unsigned short u; } c;
    c.u = u;
    return __bfloat162float(c.h);
}

// ---------------- fused fp32 -> bf16 convert of all 5 tensors ----------------
// float4-unit boundaries: src 786432 | qkv_w 442368 | proj_w 147456 | fc1_w 589824 | fc2_w 589824
__global__ void __launch_bounds__(256)
convert_all_kernel(const float* __restrict__ s0, const float* __restrict__ s1,
                   const float* __restrict__ s2, const float* __restrict__ s3,
                   const float* __restrict__ s4,
                   unsigned short* __restrict__ d0, unsigned short* __restrict__ d1,
                   unsigned short* __restrict__ d2, unsigned short* __restrict__ d3,
                   unsigned short* __restrict__ d4)
{
    const int idx = blockIdx.x * 256 + threadIdx.x;
    const float* s; unsigned short* d; int off;
    if (idx < 786432)       { s = s0; d = d0; off = idx; }
    else if (idx < 1228800) { s = s1; d = d1; off = idx - 786432; }
    else if (idx < 1376256) { s = s2; d = d2; off = idx - 1228800; }
    else if (idx < 1966080) { s = s3; d = d3; off = idx - 1376256; }
    else if (idx < 2555904) { s = s4; d = d4; off = idx - 1966080; }
    else return;
    const float4 v = ((const float4*)s)[off];
    ushort4 o;
    o.x = f2bu(v.x); o.y = f2bu(v.y); o.z = f2bu(v.z); o.w = f2bu(v.w);
    ((ushort4*)d)[off] = o;
}

// emb (H,199,HD,1) fp32 -> embpad (H,256,HD) bf16, rows r>=199 zeroed
__global__ void __launch_bounds__(256)
embpad_kernel(const float* __restrict__ rel, unsigned short* __restrict__ embpad)
{
    const int idx = blockIdx.x * 256 + threadIdx.x;   // (h*256+rp)*64+d
    if (idx >= 12 * 256 * 64) return;
    const int d = idx & 63;
    const int rp = (idx >> 6) & 255;
    const int h = idx >> 14;
    embpad[idx] = (rp < 199) ? f2bu(rel[((h * 199 + rp) << 6) + d]) : (unsigned short)0;
}

// ---------------- bf16 MFMA GEMM, NT: C[r,c] = sum_k A[r,k]*W[c,k] ----------------
// MODE 0: +bias, scatter to q (b,h,n,d) / k (b,h,n,d) / vT (b,h,d,n), bf16
// MODE 1: +bias +resid(f32) -> Cf (f32)
// MODE 2: +bias, exact GELU -> Cb (bf16)
template<int MODE>
__global__ void __launch_bounds__(256)
gemm_bf16_kernel(const unsigned short* __restrict__ A, const unsigned short* __restrict__ W,
                 const float* __restrict__ bias, const float* __restrict__ resid,
                 float* __restrict__ Cf, unsigned short* __restrict__ Cb,
                 int Ndim, int K,
                 unsigned short* __restrict__ qb, unsigned short* __restrict__ kb,
                 unsigned short* __restrict__ vTb)
{
    __shared__ short As[128 * 64];
    __shared__ short Bs[128 * 64];
    const int tid = threadIdx.x;
    const int l = tid & 63;
    const int w = tid >> 6;
    const int wr = w >> 1, wc = w & 1;
    const int row0 = blockIdx.y * 128;
    const int col0 = blockIdx.x * 128;

    f32x4 acc[4][4];
#pragma unroll
    for (int m = 0; m < 4; ++m)
#pragma unroll
        for (int n = 0; n < 4; ++n) acc[m][n] = (f32x4){0.f, 0.f, 0.f, 0.f};

    const int lrow = l >> 3;
    const int lcol = (l & 7) * 8;

    for (int k0 = 0; k0 < K; k0 += 64) {
        __syncthreads();
#pragma unroll
        for (int it = 0; it < 4; ++it) {
            const int c = w * 4 + it;
            const unsigned short* ga = A + (size_t)(row0 + c * 8 + lrow) * K + k0 + lcol;
            const unsigned short* gb = W + (size_t)(col0 + c * 8 + lrow) * K + k0 + lcol;
            GLDS16(ga, As + c * 512);
            GLDS16(gb, Bs + c * 512);
        }
        __syncthreads();
#pragma unroll
        for (int kk = 0; kk < 2; ++kk) {
            bf16x8 af[4], bfr[4];
#pragma unroll
            for (int m = 0; m < 4; ++m)
                af[m] = *(const bf16x8*)(As + (wr * 64 + m * 16 + (l & 15)) * 64 + kk * 32 + (l >> 4) * 8);
#pragma unroll
            for (int n = 0; n < 4; ++n)
                bfr[n] = *(const bf16x8*)(Bs + (wc * 64 + n * 16 + (l & 15)) * 64 + kk * 32 + (l >> 4) * 8);
#pragma unroll
            for (int m = 0; m < 4; ++m)
#pragma unroll
                for (int n = 0; n < 4; ++n)
                    acc[m][n] = __builtin_amdgcn_mfma_f32_16x16x32_bf16(af[m], bfr[n], acc[m][n], 0, 0, 0);
        }
    }

#pragma unroll
    for (int m = 0; m < 4; ++m) {
#pragma unroll
        for (int n = 0; n < 4; ++n) {
#pragma unroll
            for (int r = 0; r < 4; ++r) {
                const int row = row0 + wr * 64 + m * 16 + (l >> 4) * 4 + r;
                const int col = col0 + wc * 64 + n * 16 + (l & 15);
                float v = acc[m][n][r] + bias[col];
                if (MODE == 0) {
                    const int which = col / 768;
                    const int rem = col - which * 768;
                    const int h = rem >> 6, d = rem & 63;
                    const int b = row >> 10, nn = row & 1023;
                    if (which == 0)
                        qb[((size_t)(b * 12 + h) * 1024 + nn) * 64 + d] = f2bu(v);
                    else if (which == 1)
                        kb[((size_t)(b * 12 + h) * 1024 + nn) * 64 + d] = f2bu(v);
                    else
                        vTb[((size_t)(b * 12 + h) * 64 + d) * 1024 + nn] = f2bu(v);
                } else if (MODE == 1) {
                    const size_t idx = (size_t)row * Ndim + col;
                    Cf[idx] = v + resid[idx];
                } else {
                    const size_t idx = (size_t)row * Ndim + col;
                    const float g = 0.5f * v * (1.0f + erff(v * 0.70710678118654752f));
                    Cb[idx] = f2bu(g);
                }
            }
        }
    }
}

// ---------------- MFMA banded attention ----------------
// Block = (i0/64, h, b), 256 thr = 4 waves; wave w owns query rows i0+w*16..+15.
// Phase 1: Spos[64][r] = Qpos · Emb^T  (r 0..255, valid 0..198)   [MFMA]
// Phase 2: S = Q · K^T over banded window (<=5 col-tiles of 64)    [MFMA]
// Combine: logit = 0.125*S + Spos[i][j-i+99], mask band; softmax in regs.
// Phase 3: O = P · V  via vT tiles                                 [MFMA]
// LDS plan (58368 B):
//   ph1: Qps@0 (8K) | Stage@8K (8K) | Spos@24576 (64*264*2=33792, ends 58368)
//   ph2: Qs@0 (alias) | Stage@8K | Spos read
//   ph3: PL@0 (4*16*320*2=40960, XOR-swizzled) | Vt@40960 (8K)
__global__ void __launch_bounds__(256)
attn_mfma_kernel(const unsigned short* __restrict__ qb, const unsigned short* __restrict__ kb,
                 const unsigned short* __restrict__ vTb, const unsigned short* __restrict__ embpad,
                 unsigned short* __restrict__ ctx)
{
    __shared__ __attribute__((aligned(16))) char lds[58368];
    short* Qps = (short*)(lds);
    short* Qs = (short*)(lds);
    short* Stage = (short*)(lds + 8192);
    unsigned short* Spos = (unsigned short*)(lds + 24576);   // [64][264]
    short* PLall = (short*)(lds);                            // [4][16*320] swizzled
    short* Vt = (short*)(lds + 40960);                       // [64][64]

    const int i0 = blockIdx.x * 64;
    const int h = blockIdx.y, b = blockIdx.z;
    const int tid = threadIdx.x;
    const int l = tid & 63, w = tid >> 6;
    const int lm = l & 15, lg4 = l >> 4;
    const size_t bh = (size_t)(b * 12 + h);

    // ---- stage Qpos (fairseq flat-reshape scrambled rows) ----
#pragma unroll
    for (int c = 0; c < 2; ++c) {
        const int row = w * 16 + c * 8 + (l >> 3);
        const int iq = i0 + row;
        const int t2 = iq * 4 + b;
        const int b2 = t2 >> 10, n2 = t2 & 1023;
        const unsigned short* g = qb + ((size_t)(b2 * 12 + h) * 1024 + n2) * 64 + (l & 7) * 8;
        GLDS16(g, Qps + (w * 16 + c * 8) * 64);
    }
    __syncthreads();

    bf16x8 afp[2];
#pragma unroll
    for (int kk = 0; kk < 2; ++kk)
        afp[kk] = *(const bf16x8*)(Qps + (w * 16 + lm) * 64 + kk * 32 + lg4 * 8);

    // ---- phase 1: Spos ----
#pragma unroll
    for (int et = 0; et < 4; ++et) {
        __syncthreads();
#pragma unroll
        for (int c = 0; c < 2; ++c) {
            const int row = w * 16 + c * 8 + (l >> 3);
            const unsigned short* g = embpad + ((size_t)h * 256 + et * 64 + row) * 64 + (l & 7) * 8;
            GLDS16(g, Stage + (w * 16 + c * 8) * 64);
        }
        __syncthreads();
        f32x4 cp[4];
#pragma unroll
        for (int sub = 0; sub < 4; ++sub) cp[sub] = (f32x4){0.f, 0.f, 0.f, 0.f};
#pragma unroll
        for (int kk = 0; kk < 2; ++kk)
#pragma unroll
            for (int sub = 0; sub < 4; ++sub) {
                const bf16x8 bv = *(const bf16x8*)(Stage + (sub * 16 + lm) * 64 + kk * 32 + lg4 * 8);
                cp[sub] = __builtin_amdgcn_mfma_f32_16x16x32_bf16(afp[kk], bv, cp[sub], 0, 0, 0);
            }
#pragma unroll
        for (int sub = 0; sub < 4; ++sub)
#pragma unroll
            for (int r = 0; r < 4; ++r)
                Spos[(w * 16 + lg4 * 4 + r) * 264 + et * 64 + sub * 16 + lm] = f2bu(cp[sub][r]);
    }

    // ---- stage Q (straight rows); Qps LDS no longer read (frags in regs) ----
#pragma unroll
    for (int c = 0; c < 2; ++c) {
        const int row = w * 16 + c * 8 + (l >> 3);
        const unsigned short* g = qb + (bh * 1024 + i0 + row) * 64 + (l & 7) * 8;
        GLDS16(g, Qs + (w * 16 + c * 8) * 64);
    }

    const int jw0 = (i0 > 128) ? i0 - 128 : 0;
    const int hiex = (i0 + 163 < 1024) ? i0 + 163 : 1024;
    const int nt = (hiex - jw0 + 63) >> 6;   // 3..5 col-tiles

    f32x4 s[5][4];
#pragma unroll
    for (int ct = 0; ct < 5; ++ct)
#pragma unroll
        for (int sub = 0; sub < 4; ++sub) s[ct][sub] = (f32x4){0.f, 0.f, 0.f, 0.f};
    bf16x8 afq[2];

    // ---- phase 2: S = Q K^T over window ----
#pragma unroll
    for (int ct = 0; ct < 5; ++ct) {
        __syncthreads();
        if (ct < nt) {
#pragma unroll
            for (int c = 0; c < 2; ++c) {
                const int row = w * 16 + c * 8 + (l >> 3);
                const unsigned short* g = kb + (bh * 1024 + jw0 + ct * 64 + row) * 64 + (l & 7) * 8;
                GLDS16(g, Stage + (w * 16 + c * 8) * 64);
            }
        }
        __syncthreads();
        if (ct == 0) {
#pragma unroll
            for (int kk = 0; kk < 2; ++kk)
                afq[kk] = *(const bf16x8*)(Qs + (w * 16 + lm) * 64 + kk * 32 + lg4 * 8);
        }
        if (ct < nt) {
#pragma unroll
            for (int kk = 0; kk < 2; ++kk)
#pragma unroll
                for (int sub = 0; sub < 4; ++sub) {
                    const bf16x8 bv = *(const bf16x8*)(Stage + (sub * 16 + lm) * 64 + kk * 32 + lg4 * 8);
                    s[ct][sub] = __builtin_amdgcn_mfma_f32_16x16x32_bf16(afq[kk], bv, s[ct][sub], 0, 0, 0);
                }
        }
    }

    // ---- combine with Spos (skew) + mask; softmax in regs ----
    const int irel = w * 16 + lg4 * 4;
    float mx[4] = {-1e30f, -1e30f, -1e30f, -1e30f};
#pragma unroll
    for (int ct = 0; ct < 5; ++ct)
#pragma unroll
        for (int sub = 0; sub < 4; ++sub)
#pragma unroll
            for (int r = 0; r < 4; ++r) {
                const int i = i0 + irel + r;
                const int j = jw0 + ct * 64 + sub * 16 + lm;
                const int rr = j - i + 99;
                const int rc = (rr < 0) ? 0 : (rr > 198 ? 198 : rr);
                const float ps = bu2f(Spos[(irel + r) * 264 + rc]);
                const bool ok = (ct < nt) && (rr >= 0) && (rr <= 198);
                const float lg = ok ? (0.125f * s[ct][sub][r] + ps) : -1e30f;
                s[ct][sub][r] = lg;
                mx[r] = fmaxf(mx[r], lg);
            }
#pragma unroll
    for (int m = 1; m < 16; m <<= 1)
#pragma unroll
        for (int r = 0; r < 4; ++r) mx[r] = fmaxf(mx[r], __shfl_xor(mx[r], m, 64));

    float sm[4] = {0.f, 0.f, 0.f, 0.f};
#pragma unroll
    for (int ct = 0; ct < 5; ++ct)
#pragma unroll
        for (int sub = 0; sub < 4; ++sub)
#pragma unroll
            for (int r = 0; r < 4; ++r) {
                const float p = __expf(s[ct][sub][r] - mx[r]);
                s[ct][sub][r] = p;
                sm[r] += p;
            }
#pragma unroll
    for (int m = 1; m < 16; m <<= 1)
#pragma unroll
        for (int r = 0; r < 4; ++r) sm[r] += __shfl_xor(sm[r], m, 64);
    float inv[4];
#pragma unroll
    for (int r = 0; r < 4; ++r) inv[r] = 1.0f / sm[r];

    __syncthreads();   // all Spos reads done -> PL / Vt regions reusable

    // ---- write P to per-wave swizzled LDS (T2 XOR: conflict-free b128 reads) ----
    short* PLw = PLall + w * 5120;
#pragma unroll
    for (int ct = 0; ct < 5; ++ct)
#pragma unroll
        for (int sub = 0; sub < 4; ++sub)
#pragma unroll
            for (int r = 0; r < 4; ++r) {
                const int rowrel = lg4 * 4 + r;
                const int colrel = ct * 64 + sub * 16 + lm;
                int byte = rowrel * 640 + colrel * 2;
                byte ^= ((rowrel & 7) << 4);
                *(short*)((char*)PLw + byte) = (short)f2bu(s[ct][sub][r] * inv[r]);
            }

    // ---- phase 3: O = P V ----
    f32x4 o[4];
#pragma unroll
    for (int sub = 0; sub < 4; ++sub) o[sub] = (f32x4){0.f, 0.f, 0.f, 0.f};
#pragma unroll
    for (int ct = 0; ct < 5; ++ct) {
        if (ct < nt) {
#pragma unroll
            for (int c = 0; c < 2; ++c) {
                const int dd = w * 16 + c * 8 + (l >> 3);
                const unsigned short* g = vTb + (bh * 64 + dd) * 1024 + jw0 + ct * 64 + (l & 7) * 8;
                GLDS16(g, Vt + (w * 16 + c * 8) * 64);
            }
        }
        __syncthreads();
        if (ct < nt) {
#pragma unroll
            for (int kk = 0; kk < 2; ++kk) {
                const int colrel = ct * 64 + kk * 32 + lg4 * 8;
                int byte = lm * 640 + colrel * 2;
                byte ^= ((lm & 7) << 4);
                const bf16x8 ap = *(const bf16x8*)((char*)PLw + byte);
#pragma unroll
                for (int sub = 0; sub < 4; ++sub) {
                    const bf16x8 bv = *(const bf16x8*)(Vt + (sub * 16 + lm) * 64 + kk * 32 + lg4 * 8);
                    o[sub] = __builtin_amdgcn_mfma_f32_16x16x32_bf16(ap, bv, o[sub], 0, 0, 0);
                }
            }
        }
        __syncthreads();
    }

#pragma unroll
    for (int sub = 0; sub < 4; ++sub)
#pragma unroll
        for (int r = 0; r < 4; ++r) {
            const int i = i0 + w * 16 + lg4 * 4 + r;
            const int d = sub * 16 + lm;
            ctx[((size_t)b * 1024 + i) * 768 + h * 64 + d] = f2bu(o[sub][r]);
        }
}

// ---------------- in-place LayerNorm rows of (4096,768), optional bf16 copy ----------------
__global__ void __launch_bounds__(256)
layernorm_kernel(float* __restrict__ x, const float* __restrict__ g, const float* __restrict__ bta,
                 unsigned short* __restrict__ xb)
{
    const int row = blockIdx.x;
    float* xr = x + (size_t)row * 768;
    const int t = threadIdx.x;
    const float v0 = xr[t], v1 = xr[t + 256], v2 = xr[t + 512];
    __shared__ float red[4];
    float s = v0 + v1 + v2;
#pragma unroll
    for (int off = 32; off > 0; off >>= 1) s += __shfl_down(s, off);
    if ((t & 63) == 0) red[t >> 6] = s;
    __syncthreads();
    const float mu = (red[0] + red[1] + red[2] + red[3]) * (1.0f / 768.0f);
    __syncthreads();
    const float d0 = v0 - mu, d1 = v1 - mu, d2 = v2 - mu;
    float q = d0 * d0 + d1 * d1 + d2 * d2;
#pragma unroll
    for (int off = 32; off > 0; off >>= 1) q += __shfl_down(q, off);
    if ((t & 63) == 0) red[t >> 6] = q;
    __syncthreads();
    const float var = (red[0] + red[1] + red[2] + red[3]) * (1.0f / 768.0f);
    const float rstd = rsqrtf(var + 1e-5f);
    const float y0 = d0 * rstd * g[t] + bta[t];
    const float y1 = d1 * rstd * g[t + 256] + bta[t + 256];
    const float y2 = d2 * rstd * g[t + 512] + bta[t + 512];
    xr[t] = y0; xr[t + 256] = y1; xr[t + 512] = y2;
    if (xb) {
        unsigned short* xbr = xb + (size_t)row * 768;
        xbr[t] = f2bu(y0); xbr[t + 256] = f2bu(y1); xbr[t + 512] = f2bu(y2);
    }
}

extern "C" void kernel_launch(void* const* d_in, const int* in_sizes, int n_in,
                              void* d_out, int out_size, void* d_ws, size_t ws_size,
                              hipStream_t stream)
{
    const float* src    = (const float*)d_in[0];
    const float* qkv_w  = (const float*)d_in[1];
    const float* qkv_b  = (const float*)d_in[2];
    const float* rel    = (const float*)d_in[3];
    const float* proj_w = (const float*)d_in[4];
    const float* proj_b = (const float*)d_in[5];
    const float* ln1_g  = (const float*)d_in[6];
    const float* ln1_b  = (const float*)d_in[7];
    const float* fc1_w  = (const float*)d_in[8];
    const float* fc1_b  = (const float*)d_in[9];
    const float* fc2_w  = (const float*)d_in[10];
    const float* fc2_b  = (const float*)d_in[11];
    const float* ln2_g  = (const float*)d_in[12];
    const float* ln2_b  = (const float*)d_in[13];
    float* out = (float*)d_out;
    char* W = (char*)d_ws;

    // Workspace layout (bytes); peak 53.5 MB.
    unsigned short* k_b     = (unsigned short*)(W + 0);          // dies after attn
    unsigned short* vT_b    = (unsigned short*)(W + 6291456);    // dies after attn
    unsigned short* q_b     = (unsigned short*)(W + 12582912);   // dies after attn
    float*          xbuf    = (float*)(W + 0);                   // from proj on
    unsigned short* xbuf_b  = (unsigned short*)(W + 12582912);   // from LN1 on
    char* R2 = W + 18874368;
    unsigned short* src_b   = (unsigned short*)(R2 + 0);         // dies after QKV
    unsigned short* qkvw_b  = (unsigned short*)(R2 + 6291456);   // dies after QKV
    unsigned short* projw_b = (unsigned short*)(R2 + 9830400);   // dies after proj
    unsigned short* embp_b  = (unsigned short*)(R2 + 11010048);  // 393216 B, dies after attn
    unsigned short* ctx_b   = (unsigned short*)(R2 + 11403264);  // dies after proj
    unsigned short* h1_b    = (unsigned short*)(R2 + 0);         // from fc1 on
    unsigned short* fc1w_b  = (unsigned short*)(W + 44040192);
    unsigned short* fc2w_b  = (unsigned short*)(W + 48758784);

    // 0) converts (one fused launch + emb pad/convert)
    convert_all_kernel<<<9984, 256, 0, stream>>>(
        src, qkv_w, proj_w, fc1_w, fc2_w, src_b, qkvw_b, projw_b, fc1w_b, fc2w_b);
    embpad_kernel<<<768, 256, 0, stream>>>(rel, embp_b);

    // 1) QKV: (4096x768)@(2304x768)^T, scatter q/k/vT bf16
    gemm_bf16_kernel<0><<<dim3(2304 / 128, 4096 / 128), 256, 0, stream>>>(
        src_b, qkvw_b, qkv_b, nullptr, nullptr, nullptr, 2304, 768, q_b, k_b, vT_b);

    // 2) MFMA banded attention -> ctx bf16
    attn_mfma_kernel<<<dim3(16, 12, 4), 256, 0, stream>>>(q_b, k_b, vT_b, embp_b, ctx_b);

    // 3) proj + bias + src residual -> xbuf f32
    gemm_bf16_kernel<1><<<dim3(768 / 128, 4096 / 128), 256, 0, stream>>>(
        ctx_b, projw_b, proj_b, src, xbuf, nullptr, 768, 768, nullptr, nullptr, nullptr);

    // 4) LN1 in place + bf16 copy
    layernorm_kernel<<<4096, 256, 0, stream>>>(xbuf, ln1_g, ln1_b, xbuf_b);

    // 5) fc1 + bias + GELU -> h1 bf16
    gemm_bf16_kernel<2><<<dim3(3072 / 128, 4096 / 128), 256, 0, stream>>>(
        xbuf_b, fc1w_b, fc1_b, nullptr, nullptr, h1_b, 3072, 768, nullptr, nullptr, nullptr);

    // 6) fc2 + bias + xbuf residual -> out f32
    gemm_bf16_kernel<1><<<dim3(768 / 128, 4096 / 128), 256, 0, stream>>>(
        h1_b, fc2w_b, fc2_b, xbuf, out, nullptr, 768, 3072, nullptr, nullptr, nullptr);

    // 7) LN2 in place
    layernorm_kernel<<<4096, 256, 0, stream>>>(out, ln2_g, ln2_b, nullptr);
}

// Round 8
// 203.320 us; speedup vs baseline: 9.6753x; 1.2820x over previous
//
#include <hip/hip_runtime.h>
#include <hip/hip_bf16.h>
#include <math.h>

// B=4, N=1024, D=768, H=12, HD=64, M=100, FF=3072
// Attention EXACTLY banded radius 99. Round 7: same kernels as R6; FIX the
// workspace layout bug (PP/FP split-K partials were sized in bytes where the
// pointer math was in elements -> clobbered fc1/fc2 weights; absmax 2.55).

typedef __attribute__((ext_vector_type(8))) short bf16x8;
typedef __attribute__((ext_vector_type(4))) float f32x4;

#define GLDS16(g, l) __builtin_amdgcn_global_load_lds( \
    (const __attribute__((address_space(1))) void*)(g), \
    (__attribute__((address_space(3))) void*)(l), 16, 0, 0)

__device__ __forceinline__ unsigned short f2bu(float x) {
    union { __hip_bfloat16 h; unsigned short u; } c;
    c.h = __float2bfloat16(x);
    return c.u;
}
__device__ __forceinline__ float bu2f(unsigned short u) {
    union { __hip_bfloat16 h; unsigned short u; } c;
    c.u = u;
    return __bfloat162float(c.h);
}

// ---------------- fused fp32 -> bf16 convert of all 5 tensors ----------------
__global__ void __launch_bounds__(256)
convert_all_kernel(const float* __restrict__ s0, const float* __restrict__ s1,
                   const float* __restrict__ s2, const float* __restrict__ s3,
                   const float* __restrict__ s4,
                   unsigned short* __restrict__ d0, unsigned short* __restrict__ d1,
                   unsigned short* __restrict__ d2, unsigned short* __restrict__ d3,
                   unsigned short* __restrict__ d4)
{
    const int idx = blockIdx.x * 256 + threadIdx.x;
    const float* s; unsigned short* d; int off;
    if (idx < 786432)       { s = s0; d = d0; off = idx; }
    else if (idx < 1228800) { s = s1; d = d1; off = idx - 786432; }
    else if (idx < 1376256) { s = s2; d = d2; off = idx - 1228800; }
    else if (idx < 1966080) { s = s3; d = d3; off = idx - 1376256; }
    else if (idx < 2555904) { s = s4; d = d4; off = idx - 1966080; }
    else return;
    const float4 v = ((const float4*)s)[off];
    ushort4 o;
    o.x = f2bu(v.x); o.y = f2bu(v.y); o.z = f2bu(v.z); o.w = f2bu(v.w);
    ((ushort4*)d)[off] = o;
}

// emb (H,199,HD,1) fp32 -> embpad (H,256,HD) bf16, rows r>=199 zeroed
__global__ void __launch_bounds__(256)
embpad_kernel(const float* __restrict__ rel, unsigned short* __restrict__ embpad)
{
    const int idx = blockIdx.x * 256 + threadIdx.x;
    if (idx >= 12 * 256 * 64) return;
    const int d = idx & 63;
    const int rp = (idx >> 6) & 255;
    const int h = idx >> 14;
    embpad[idx] = (rp < 199) ? f2bu(rel[((h * 199 + rp) << 6) + d]) : (unsigned short)0;
}

// ---------------- bf16 MFMA GEMM, NT, 128x64 tile, dbuf LDS ----------------
// 256 thr = 4 waves (2 row x 2 col), wave = 64x32 out = 4x2 frags 16x16x32.
// MODE 0: +bias, scatter q (b,h,n,d) / k (b,h,n,d) / vT (b,h,d,n) bf16
// MODE 2: +bias, exact GELU -> Cb bf16
// MODE 3: raw partial -> Cb + blockIdx.z*4096*Ndim elements (bf16)
template<int MODE>
__global__ void __launch_bounds__(256)
gemm64_kernel(const unsigned short* __restrict__ A, const unsigned short* __restrict__ Wt,
              const float* __restrict__ bias, unsigned short* __restrict__ Cb,
              int Ndim, int K, int Ksplit,
              unsigned short* __restrict__ qb, unsigned short* __restrict__ kb,
              unsigned short* __restrict__ vTb)
{
    __shared__ short As[2 * 128 * 64];   // 2 x 16 KB
    __shared__ short Bs[2 * 64 * 64];    // 2 x 8 KB
    const int tid = threadIdx.x;
    const int l = tid & 63;
    const int w = tid >> 6;
    const int wr = w >> 1, wc = w & 1;

    // XCD-aware swizzle of flattened xy (nxy % 8 == 0 for all our grids)
    int flat = blockIdx.y * gridDim.x + blockIdx.x;
    const int nxy = gridDim.x * gridDim.y;
    flat = (flat & 7) * (nxy >> 3) + (flat >> 3);
    const int bx = flat % gridDim.x;
    const int by = flat / gridDim.x;

    const int row0 = by * 128;
    const int col0 = bx * 64;
    const int koff = blockIdx.z * Ksplit;
    const int nt = Ksplit >> 6;

    const int lrow = l >> 3;          // 0..7
    const int lcol = (l & 7) * 8;     // 0..56

    f32x4 acc[4][2];
#pragma unroll
    for (int m = 0; m < 4; ++m)
#pragma unroll
        for (int n = 0; n < 2; ++n) acc[m][n] = (f32x4){0.f, 0.f, 0.f, 0.f};

    // stage K-tile t into buffer buf
#define STAGE(buf, t) do {                                                        \
    const int k0 = koff + (t) * 64;                                               \
    _Pragma("unroll")                                                             \
    for (int it = 0; it < 4; ++it) {                                              \
        const int c = w * 4 + it;                                                 \
        GLDS16(A + (size_t)(row0 + c * 8 + lrow) * K + k0 + lcol,                 \
               As + (buf) * 8192 + c * 512);                                      \
    }                                                                             \
    _Pragma("unroll")                                                             \
    for (int it = 0; it < 2; ++it) {                                              \
        const int c = w * 2 + it;                                                 \
        GLDS16(Wt + (size_t)(col0 + c * 8 + lrow) * K + k0 + lcol,                \
               Bs + (buf) * 4096 + c * 512);                                      \
    }                                                                             \
} while (0)

    STAGE(0, 0);
    __syncthreads();                      // vmcnt(0) drained by compiler

    for (int t = 0; t < nt; ++t) {
        const int buf = t & 1;
        if (t + 1 < nt) STAGE(buf ^ 1, t + 1);   // overlaps with compute below
        const short* a = As + buf * 8192;
        const short* bsp = Bs + buf * 4096;
#pragma unroll
        for (int kk = 0; kk < 2; ++kk) {
            bf16x8 af[4], bfr[2];
#pragma unroll
            for (int m = 0; m < 4; ++m)
                af[m] = *(const bf16x8*)(a + (wr * 64 + m * 16 + (l & 15)) * 64 + kk * 32 + (l >> 4) * 8);
#pragma unroll
            for (int n = 0; n < 2; ++n)
                bfr[n] = *(const bf16x8*)(bsp + (wc * 32 + n * 16 + (l & 15)) * 64 + kk * 32 + (l >> 4) * 8);
#pragma unroll
            for (int m = 0; m < 4; ++m)
#pragma unroll
                for (int n = 0; n < 2; ++n)
                    acc[m][n] = __builtin_amdgcn_mfma_f32_16x16x32_bf16(af[m], bfr[n], acc[m][n], 0, 0, 0);
        }
        if (t + 1 < nt) __syncthreads();  // uniform; drains stage + cross-wave reads
    }
#undef STAGE

    // Epilogue. D map: col = lane&15, row = (lane>>4)*4 + reg
#pragma unroll
    for (int m = 0; m < 4; ++m) {
#pragma unroll
        for (int n = 0; n < 2; ++n) {
#pragma unroll
            for (int r = 0; r < 4; ++r) {
                const int row = row0 + wr * 64 + m * 16 + (l >> 4) * 4 + r;
                const int col = col0 + wc * 32 + n * 16 + (l & 15);
                if (MODE == 0) {
                    const float v = acc[m][n][r] + bias[col];
                    const int which = col / 768;
                    const int rem = col - which * 768;
                    const int h = rem >> 6, d = rem & 63;
                    const int b = row >> 10, nn = row & 1023;
                    if (which == 0)
                        qb[((size_t)(b * 12 + h) * 1024 + nn) * 64 + d] = f2bu(v);
                    else if (which == 1)
                        kb[((size_t)(b * 12 + h) * 1024 + nn) * 64 + d] = f2bu(v);
                    else
                        vTb[((size_t)(b * 12 + h) * 64 + d) * 1024 + nn] = f2bu(v);
                } else if (MODE == 2) {
                    const float v = acc[m][n][r] + bias[col];
                    const float g = 0.5f * v * (1.0f + erff(v * 0.70710678118654752f));
                    Cb[(size_t)row * Ndim + col] = f2bu(g);
                } else {
                    unsigned short* dst = Cb + (size_t)blockIdx.z * 4096 * Ndim;
                    dst[(size_t)row * Ndim + col] = f2bu(acc[m][n][r]);
                }
            }
        }
    }
}

// ---------------- MFMA banded attention (unchanged from R5) ----------------
__global__ void __launch_bounds__(256)
attn_mfma_kernel(const unsigned short* __restrict__ qb, const unsigned short* __restrict__ kb,
                 const unsigned short* __restrict__ vTb, const unsigned short* __restrict__ embpad,
                 unsigned short* __restrict__ ctx)
{
    __shared__ __attribute__((aligned(16))) char lds[58368];
    short* Qps = (short*)(lds);
    short* Qs = (short*)(lds);
    short* Stage = (short*)(lds + 8192);
    unsigned short* Spos = (unsigned short*)(lds + 24576);   // [64][264]
    short* PLall = (short*)(lds);                            // [4][16*320] swizzled
    short* Vt = (short*)(lds + 40960);                       // [64][64]

    const int i0 = blockIdx.x * 64;
    const int h = blockIdx.y, b = blockIdx.z;
    const int tid = threadIdx.x;
    const int l = tid & 63, w = tid >> 6;
    const int lm = l & 15, lg4 = l >> 4;
    const size_t bh = (size_t)(b * 12 + h);

#pragma unroll
    for (int c = 0; c < 2; ++c) {
        const int row = w * 16 + c * 8 + (l >> 3);
        const int iq = i0 + row;
        const int t2 = iq * 4 + b;
        const int b2 = t2 >> 10, n2 = t2 & 1023;
        const unsigned short* g = qb + ((size_t)(b2 * 12 + h) * 1024 + n2) * 64 + (l & 7) * 8;
        GLDS16(g, Qps + (w * 16 + c * 8) * 64);
    }
    __syncthreads();

    bf16x8 afp[2];
#pragma unroll
    for (int kk = 0; kk < 2; ++kk)
        afp[kk] = *(const bf16x8*)(Qps + (w * 16 + lm) * 64 + kk * 32 + lg4 * 8);

#pragma unroll
    for (int et = 0; et < 4; ++et) {
        __syncthreads();
#pragma unroll
        for (int c = 0; c < 2; ++c) {
            const int row = w * 16 + c * 8 + (l >> 3);
            const unsigned short* g = embpad + ((size_t)h * 256 + et * 64 + row) * 64 + (l & 7) * 8;
            GLDS16(g, Stage + (w * 16 + c * 8) * 64);
        }
        __syncthreads();
        f32x4 cp[4];
#pragma unroll
        for (int sub = 0; sub < 4; ++sub) cp[sub] = (f32x4){0.f, 0.f, 0.f, 0.f};
#pragma unroll
        for (int kk = 0; kk < 2; ++kk)
#pragma unroll
            for (int sub = 0; sub < 4; ++sub) {
                const bf16x8 bv = *(const bf16x8*)(Stage + (sub * 16 + lm) * 64 + kk * 32 + lg4 * 8);
                cp[sub] = __builtin_amdgcn_mfma_f32_16x16x32_bf16(afp[kk], bv, cp[sub], 0, 0, 0);
            }
#pragma unroll
        for (int sub = 0; sub < 4; ++sub)
#pragma unroll
            for (int r = 0; r < 4; ++r)
                Spos[(w * 16 + lg4 * 4 + r) * 264 + et * 64 + sub * 16 + lm] = f2bu(cp[sub][r]);
    }

#pragma unroll
    for (int c = 0; c < 2; ++c) {
        const int row = w * 16 + c * 8 + (l >> 3);
        const unsigned short* g = qb + (bh * 1024 + i0 + row) * 64 + (l & 7) * 8;
        GLDS16(g, Qs + (w * 16 + c * 8) * 64);
    }

    const int jw0 = (i0 > 128) ? i0 - 128 : 0;
    const int hiex = (i0 + 163 < 1024) ? i0 + 163 : 1024;
    const int nt = (hiex - jw0 + 63) >> 6;

    f32x4 s[5][4];
#pragma unroll
    for (int ct = 0; ct < 5; ++ct)
#pragma unroll
        for (int sub = 0; sub < 4; ++sub) s[ct][sub] = (f32x4){0.f, 0.f, 0.f, 0.f};
    bf16x8 afq[2];

#pragma unroll
    for (int ct = 0; ct < 5; ++ct) {
        __syncthreads();
        if (ct < nt) {
#pragma unroll
            for (int c = 0; c < 2; ++c) {
                const int row = w * 16 + c * 8 + (l >> 3);
                const unsigned short* g = kb + (bh * 1024 + jw0 + ct * 64 + row) * 64 + (l & 7) * 8;
                GLDS16(g, Stage + (w * 16 + c * 8) * 64);
            }
        }
        __syncthreads();
        if (ct == 0) {
#pragma unroll
            for (int kk = 0; kk < 2; ++kk)
                afq[kk] = *(const bf16x8*)(Qs + (w * 16 + lm) * 64 + kk * 32 + lg4 * 8);
        }
        if (ct < nt) {
#pragma unroll
            for (int kk = 0; kk < 2; ++kk)
#pragma unroll
                for (int sub = 0; sub < 4; ++sub) {
                    const bf16x8 bv = *(const bf16x8*)(Stage + (sub * 16 + lm) * 64 + kk * 32 + lg4 * 8);
                    s[ct][sub] = __builtin_amdgcn_mfma_f32_16x16x32_bf16(afq[kk], bv, s[ct][sub], 0, 0, 0);
                }
        }
    }

    const int irel = w * 16 + lg4 * 4;
    float mx[4] = {-1e30f, -1e30f, -1e30f, -1e30f};
#pragma unroll
    for (int ct = 0; ct < 5; ++ct)
#pragma unroll
        for (int sub = 0; sub < 4; ++sub)
#pragma unroll
            for (int r = 0; r < 4; ++r) {
                const int i = i0 + irel + r;
                const int j = jw0 + ct * 64 + sub * 16 + lm;
                const int rr = j - i + 99;
                const int rc = (rr < 0) ? 0 : (rr > 198 ? 198 : rr);
                const float ps = bu2f(Spos[(irel + r) * 264 + rc]);
                const bool ok = (ct < nt) && (rr >= 0) && (rr <= 198);
                const float lg = ok ? (0.125f * s[ct][sub][r] + ps) : -1e30f;
                s[ct][sub][r] = lg;
                mx[r] = fmaxf(mx[r], lg);
            }
#pragma unroll
    for (int m = 1; m < 16; m <<= 1)
#pragma unroll
        for (int r = 0; r < 4; ++r) mx[r] = fmaxf(mx[r], __shfl_xor(mx[r], m, 64));

    float sm[4] = {0.f, 0.f, 0.f, 0.f};
#pragma unroll
    for (int ct = 0; ct < 5; ++ct)
#pragma unroll
        for (int sub = 0; sub < 4; ++sub)
#pragma unroll
            for (int r = 0; r < 4; ++r) {
                const float p = __expf(s[ct][sub][r] - mx[r]);
                s[ct][sub][r] = p;
                sm[r] += p;
            }
#pragma unroll
    for (int m = 1; m < 16; m <<= 1)
#pragma unroll
        for (int r = 0; r < 4; ++r) sm[r] += __shfl_xor(sm[r], m, 64);
    float inv[4];
#pragma unroll
    for (int r = 0; r < 4; ++r) inv[r] = 1.0f / sm[r];

    __syncthreads();

    short* PLw = PLall + w * 5120;
#pragma unroll
    for (int ct = 0; ct < 5; ++ct)
#pragma unroll
        for (int sub = 0; sub < 4; ++sub)
#pragma unroll
            for (int r = 0; r < 4; ++r) {
                const int rowrel = lg4 * 4 + r;
                const int colrel = ct * 64 + sub * 16 + lm;
                int byte = rowrel * 640 + colrel * 2;
                byte ^= ((rowrel & 7) << 4);
                *(short*)((char*)PLw + byte) = (short)f2bu(s[ct][sub][r] * inv[r]);
            }

    f32x4 o[4];
#pragma unroll
    for (int sub = 0; sub < 4; ++sub) o[sub] = (f32x4){0.f, 0.f, 0.f, 0.f};
#pragma unroll
    for (int ct = 0; ct < 5; ++ct) {
        if (ct < nt) {
#pragma unroll
            for (int c = 0; c < 2; ++c) {
                const int dd = w * 16 + c * 8 + (l >> 3);
                const unsigned short* g = vTb + (bh * 64 + dd) * 1024 + jw0 + ct * 64 + (l & 7) * 8;
                GLDS16(g, Vt + (w * 16 + c * 8) * 64);
            }
        }
        __syncthreads();
        if (ct < nt) {
#pragma unroll
            for (int kk = 0; kk < 2; ++kk) {
                const int colrel = ct * 64 + kk * 32 + lg4 * 8;
                int byte = lm * 640 + colrel * 2;
                byte ^= ((lm & 7) << 4);
                const bf16x8 ap = *(const bf16x8*)((char*)PLw + byte);
#pragma unroll
                for (int sub = 0; sub < 4; ++sub) {
                    const bf16x8 bv = *(const bf16x8*)(Vt + (sub * 16 + lm) * 64 + kk * 32 + lg4 * 8);
                    o[sub] = __builtin_amdgcn_mfma_f32_16x16x32_bf16(ap, bv, o[sub], 0, 0, 0);
                }
            }
        }
        __syncthreads();
    }

#pragma unroll
    for (int sub = 0; sub < 4; ++sub)
#pragma unroll
        for (int r = 0; r < 4; ++r) {
            const int i = i0 + w * 16 + lg4 * 4 + r;
            const int d = sub * 16 + lm;
            ctx[((size_t)b * 1024 + i) * 768 + h * 64 + d] = f2bu(o[sub][r]);
        }
}

// ---------------- fused split-K reduce + bias + residual + LayerNorm ----------------
__global__ void __launch_bounds__(256)
ln_fuse_kernel(const unsigned short* __restrict__ p0, const unsigned short* __restrict__ p1,
               const float* __restrict__ bias,
               const float* __restrict__ residf, const unsigned short* __restrict__ residb,
               const float* __restrict__ g, const float* __restrict__ bta,
               float* __restrict__ outf, unsigned short* __restrict__ outb)
{
    const int row = blockIdx.x;
    const int t = threadIdx.x;
    const size_t base = (size_t)row * 768;
    float v[3];
#pragma unroll
    for (int e = 0; e < 3; ++e) {
        const int idx = t + e * 256;
        const float r = residf ? residf[base + idx] : bu2f(residb[base + idx]);
        v[e] = bu2f(p0[base + idx]) + bu2f(p1[base + idx]) + bias[idx] + r;
    }
    __shared__ float red[4];
    float s = v[0] + v[1] + v[2];
#pragma unroll
    for (int off = 32; off > 0; off >>= 1) s += __shfl_down(s, off);
    if ((t & 63) == 0) red[t >> 6] = s;
    __syncthreads();
    const float mu = (red[0] + red[1] + red[2] + red[3]) * (1.0f / 768.0f);
    __syncthreads();
    const float d0 = v[0] - mu, d1 = v[1] - mu, d2 = v[2] - mu;
    float q = d0 * d0 + d1 * d1 + d2 * d2;
#pragma unroll
    for (int off = 32; off > 0; off >>= 1) q += __shfl_down(q, off);
    if ((t & 63) == 0) red[t >> 6] = q;
    __syncthreads();
    const float var = (red[0] + red[1] + red[2] + red[3]) * (1.0f / 768.0f);
    const float rstd = rsqrtf(var + 1e-5f);
    const float y0 = d0 * rstd * g[t] + bta[t];
    const float y1 = d1 * rstd * g[t + 256] + bta[t + 256];
    const float y2 = d2 * rstd * g[t + 512] + bta[t + 512];
    if (outf) { outf[base + t] = y0; outf[base + t + 256] = y1; outf[base + t + 512] = y2; }
    if (outb) { outb[base + t] = f2bu(y0); outb[base + t + 256] = f2bu(y1); outb[base + t + 512] = f2bu(y2); }
}

extern "C" void kernel_launch(void* const* d_in, const int* in_sizes, int n_in,
                              void* d_out, int out_size, void* d_ws, size_t ws_size,
                              hipStream_t stream)
{
    const float* src    = (const float*)d_in[0];
    const float* qkv_w  = (const float*)d_in[1];
    const float* qkv_b  = (const float*)d_in[2];
    const float* rel    = (const float*)d_in[3];
    const float* proj_w = (const float*)d_in[4];
    const float* proj_b = (const float*)d_in[5];
    const float* ln1_g  = (const float*)d_in[6];
    const float* ln1_b  = (const float*)d_in[7];
    const float* fc1_w  = (const float*)d_in[8];
    const float* fc1_b  = (const float*)d_in[9];
    const float* fc2_w  = (const float*)d_in[10];
    const float* fc2_b  = (const float*)d_in[11];
    const float* ln2_g  = (const float*)d_in[12];
    const float* ln2_b  = (const float*)d_in[13];
    float* out = (float*)d_out;
    char* W = (char*)d_ws;

    // Workspace layout (FIXED: PP/FP are 2 x 6291456 B = 12582912 B each).
    // Peak 55050240 B = 52.5 MB (< 60 MB proven in R1). Lifetimes:
    //   [0,18874368)         q_b|k_b|vT_b (steps 1-2); then h1_b [0,25165824) (5-6)
    //   [18874368,25165824)  src_b (conv->1), then ctx_b (2->3)
    //   [25165824,37748736)  qkvw_b (conv->1, first 3538944 B), then PP (3->4), then FP (6->7)
    //   [37748736,38928384)  projw_b (conv->3)
    //   [38928384,43646976)  fc1w_b (conv->5)
    //   [43646976,48365568)  fc2w_b (conv->6)
    //   [48365568,48758784)  embp_b (conv->2)
    //   [48758784,55050240)  xbuf_b (4->7)
    unsigned short* q_b     = (unsigned short*)(W + 0);
    unsigned short* k_b     = (unsigned short*)(W + 6291456);
    unsigned short* vT_b    = (unsigned short*)(W + 12582912);
    unsigned short* src_b   = (unsigned short*)(W + 18874368);
    unsigned short* ctx_b   = (unsigned short*)(W + 18874368);
    unsigned short* h1_b    = (unsigned short*)(W + 0);
    unsigned short* qkvw_b  = (unsigned short*)(W + 25165824);
    unsigned short* PP      = (unsigned short*)(W + 25165824);  // PP0 | PP1 (2 x 6291456 B)
    unsigned short* FP      = (unsigned short*)(W + 25165824);  // FP0 | FP1 (2 x 6291456 B)
    unsigned short* projw_b = (unsigned short*)(W + 37748736);
    unsigned short* fc1w_b  = (unsigned short*)(W + 38928384);
    unsigned short* fc2w_b  = (unsigned short*)(W + 43646976);
    unsigned short* embp_b  = (unsigned short*)(W + 48365568);
    unsigned short* xbuf_b  = (unsigned short*)(W + 48758784);

    // 0) converts
    convert_all_kernel<<<9984, 256, 0, stream>>>(
        src, qkv_w, proj_w, fc1_w, fc2_w, src_b, qkvw_b, projw_b, fc1w_b, fc2w_b);
    embpad_kernel<<<768, 256, 0, stream>>>(rel, embp_b);

    // 1) QKV: (4096x768)@(2304x768)^T -> scatter q/k/vT
    gemm64_kernel<0><<<dim3(36, 32, 1), 256, 0, stream>>>(
        src_b, qkvw_b, qkv_b, nullptr, 2304, 768, 768, q_b, k_b, vT_b);

    // 2) banded MFMA attention -> ctx bf16
    attn_mfma_kernel<<<dim3(16, 12, 4), 256, 0, stream>>>(q_b, k_b, vT_b, embp_b, ctx_b);

    // 3) proj, split-K x2 -> PP0/PP1 partials (bf16)
    gemm64_kernel<3><<<dim3(12, 32, 2), 256, 0, stream>>>(
        ctx_b, projw_b, nullptr, PP, 768, 768, 384, nullptr, nullptr, nullptr);

    // 4) LN1 = PP0+PP1+proj_b+src -> LN -> xbuf_b
    ln_fuse_kernel<<<4096, 256, 0, stream>>>(
        PP, PP + 4096 * 768, proj_b, src, nullptr, ln1_g, ln1_b, nullptr, xbuf_b);

    // 5) fc1 + bias + GELU -> h1 bf16
    gemm64_kernel<2><<<dim3(48, 32, 1), 256, 0, stream>>>(
        xbuf_b, fc1w_b, fc1_b, h1_b, 3072, 768, 768, nullptr, nullptr, nullptr);

    // 6) fc2, split-K x2 (K=3072 -> 2x1536) -> FP0/FP1
    gemm64_kernel<3><<<dim3(12, 32, 2), 256, 0, stream>>>(
        h1_b, fc2w_b, nullptr, FP, 768, 3072, 1536, nullptr, nullptr, nullptr);

    // 7) LN2 = FP0+FP1+fc2_b+xbuf_b -> LN -> out (f32)
    ln_fuse_kernel<<<4096, 256, 0, stream>>>(
        FP, FP + 4096 * 768, fc2_b, nullptr, xbuf_b, ln2_g, ln2_b, out, nullptr);
}

// Round 9
// 171.101 us; speedup vs baseline: 11.4972x; 1.1883x over previous
//
#include <hip/hip_runtime.h>
#include <hip/hip_bf16.h>
#include <math.h>

// B=4, N=1024, D=768, H=12, HD=64, M=100, FF=3072
// Attention EXACTLY banded radius 99. Round 9: T2 LDS bank-conflict fix —
// pre-swizzled global_load_lds source (lane l stages chunk (l&7)^(l>>3)) +
// XOR'd fragment reads (chunk ^ (row&7)) in BOTH gemm64 and attn kernels.
// fc1 GELU switched to tanh/__expf form (cheaper VALU than erff).

typedef __attribute__((ext_vector_type(8))) short bf16x8;
typedef __attribute__((ext_vector_type(4))) float f32x4;

#define GLDS16(g, l) __builtin_amdgcn_global_load_lds( \
    (const __attribute__((address_space(1))) void*)(g), \
    (__attribute__((address_space(3))) void*)(l), 16, 0, 0)

__device__ __forceinline__ unsigned short f2bu(float x) {
    union { __hip_bfloat16 h; unsigned short u; } c;
    c.h = __float2bfloat16(x);
    return c.u;
}
__device__ __forceinline__ float bu2f(unsigned short u) {
    union { __hip_bfloat16 h; unsigned short u; } c;
    c.u = u;
    return __bfloat162float(c.h);
}

// ---------------- fused fp32 -> bf16 convert of all 5 tensors ----------------
__global__ void __launch_bounds__(256)
convert_all_kernel(const float* __restrict__ s0, const float* __restrict__ s1,
                   const float* __restrict__ s2, const float* __restrict__ s3,
                   const float* __restrict__ s4,
                   unsigned short* __restrict__ d0, unsigned short* __restrict__ d1,
                   unsigned short* __restrict__ d2, unsigned short* __restrict__ d3,
                   unsigned short* __restrict__ d4)
{
    const int idx = blockIdx.x * 256 + threadIdx.x;
    const float* s; unsigned short* d; int off;
    if (idx < 786432)       { s = s0; d = d0; off = idx; }
    else if (idx < 1228800) { s = s1; d = d1; off = idx - 786432; }
    else if (idx < 1376256) { s = s2; d = d2; off = idx - 1228800; }
    else if (idx < 1966080) { s = s3; d = d3; off = idx - 1376256; }
    else if (idx < 2555904) { s = s4; d = d4; off = idx - 1966080; }
    else return;
    const float4 v = ((const float4*)s)[off];
    ushort4 o;
    o.x = f2bu(v.x); o.y = f2bu(v.y); o.z = f2bu(v.z); o.w = f2bu(v.w);
    ((ushort4*)d)[off] = o;
}

// emb (H,199,HD,1) fp32 -> embpad (H,256,HD) bf16, rows r>=199 zeroed
__global__ void __launch_bounds__(256)
embpad_kernel(const float* __restrict__ rel, unsigned short* __restrict__ embpad)
{
    const int idx = blockIdx.x * 256 + threadIdx.x;
    if (idx >= 12 * 256 * 64) return;
    const int d = idx & 63;
    const int rp = (idx >> 6) & 255;
    const int h = idx >> 14;
    embpad[idx] = (rp < 199) ? f2bu(rel[((h * 199 + rp) << 6) + d]) : (unsigned short)0;
}

// Swizzle helper for fragment reads from gload-staged [row][64]-short tiles:
// LDS(row, c) holds global chunk c ^ (row&7); to read global chunk ch of row r
// use LDS chunk ch ^ (r&7). Chunks are 8 shorts = 16 B.
#define SWZ_OFF(ch, row7) ((((ch) ^ (row7)) * 8))

// ---------------- bf16 MFMA GEMM, NT, 128x64 tile, dbuf LDS, swizzled ----------------
// MODE 0: +bias, scatter q (b,h,n,d) / k (b,h,n,d) / vT (b,h,d,n) bf16
// MODE 2: +bias, tanh-GELU -> Cb bf16
// MODE 3: raw partial -> Cb + blockIdx.z*4096*Ndim elements (bf16)
template<int MODE>
__global__ void __launch_bounds__(256)
gemm64_kernel(const unsigned short* __restrict__ A, const unsigned short* __restrict__ Wt,
              const float* __restrict__ bias, unsigned short* __restrict__ Cb,
              int Ndim, int K, int Ksplit,
              unsigned short* __restrict__ qb, unsigned short* __restrict__ kb,
              unsigned short* __restrict__ vTb)
{
    __shared__ short As[2 * 128 * 64];   // 2 x 16 KB
    __shared__ short Bs[2 * 64 * 64];    // 2 x 8 KB
    const int tid = threadIdx.x;
    const int l = tid & 63;
    const int w = tid >> 6;
    const int wr = w >> 1, wc = w & 1;

    // XCD-aware swizzle of flattened xy (nxy % 8 == 0 for all our grids)
    int flat = blockIdx.y * gridDim.x + blockIdx.x;
    const int nxy = gridDim.x * gridDim.y;
    flat = (flat & 7) * (nxy >> 3) + (flat >> 3);
    const int bx = flat % gridDim.x;
    const int by = flat / gridDim.x;

    const int row0 = by * 128;
    const int col0 = bx * 64;
    const int koff = blockIdx.z * Ksplit;
    const int nt = Ksplit >> 6;

    const int lrow = l >> 3;                      // 0..7
    const int lcol = ((l & 7) ^ lrow) * 8;        // PRE-SWIZZLED source chunk
    const int l7 = l & 7;                          // == (row&7) for all our frag rows

    f32x4 acc[4][2];
#pragma unroll
    for (int m = 0; m < 4; ++m)
#pragma unroll
        for (int n = 0; n < 2; ++n) acc[m][n] = (f32x4){0.f, 0.f, 0.f, 0.f};

    // stage K-tile t into buffer buf (LDS dest linear: lane l -> byte l*16)
#define STAGE(buf, t) do {                                                        \
    const int k0 = koff + (t) * 64;                                               \
    _Pragma("unroll")                                                             \
    for (int it = 0; it < 4; ++it) {                                              \
        const int c = w * 4 + it;                                                 \
        GLDS16(A + (size_t)(row0 + c * 8 + lrow) * K + k0 + lcol,                 \
               As + (buf) * 8192 + c * 512);                                      \
    }                                                                             \
    _Pragma("unroll")                                                             \
    for (int it = 0; it < 2; ++it) {                                              \
        const int c = w * 2 + it;                                                 \
        GLDS16(Wt + (size_t)(col0 + c * 8 + lrow) * K + k0 + lcol,                \
               Bs + (buf) * 4096 + c * 512);                                      \
    }                                                                             \
} while (0)

    STAGE(0, 0);
    __syncthreads();                      // vmcnt(0) drained by compiler

    for (int t = 0; t < nt; ++t) {
        const int buf = t & 1;
        if (t + 1 < nt) STAGE(buf ^ 1, t + 1);   // overlaps with compute below
        const short* a = As + buf * 8192;
        const short* bsp = Bs + buf * 4096;
#pragma unroll
        for (int kk = 0; kk < 2; ++kk) {
            const int ch = kk * 4 + (l >> 4);     // logical 16B chunk 0..7
            bf16x8 af[4], bfr[2];
#pragma unroll
            for (int m = 0; m < 4; ++m)
                af[m] = *(const bf16x8*)(a + (wr * 64 + m * 16 + (l & 15)) * 64 + SWZ_OFF(ch, l7));
#pragma unroll
            for (int n = 0; n < 2; ++n)
                bfr[n] = *(const bf16x8*)(bsp + (wc * 32 + n * 16 + (l & 15)) * 64 + SWZ_OFF(ch, l7));
#pragma unroll
            for (int m = 0; m < 4; ++m)
#pragma unroll
                for (int n = 0; n < 2; ++n)
                    acc[m][n] = __builtin_amdgcn_mfma_f32_16x16x32_bf16(af[m], bfr[n], acc[m][n], 0, 0, 0);
        }
        if (t + 1 < nt) __syncthreads();  // uniform; drains stage + cross-wave reads
    }
#undef STAGE

    // Epilogue. D map: col = lane&15, row = (lane>>4)*4 + reg
#pragma unroll
    for (int m = 0; m < 4; ++m) {
#pragma unroll
        for (int n = 0; n < 2; ++n) {
#pragma unroll
            for (int r = 0; r < 4; ++r) {
                const int row = row0 + wr * 64 + m * 16 + (l >> 4) * 4 + r;
                const int col = col0 + wc * 32 + n * 16 + (l & 15);
                if (MODE == 0) {
                    const float v = acc[m][n][r] + bias[col];
                    const int which = col / 768;
                    const int rem = col - which * 768;
                    const int h = rem >> 6, d = rem & 63;
                    const int b = row >> 10, nn = row & 1023;
                    if (which == 0)
                        qb[((size_t)(b * 12 + h) * 1024 + nn) * 64 + d] = f2bu(v);
                    else if (which == 1)
                        kb[((size_t)(b * 12 + h) * 1024 + nn) * 64 + d] = f2bu(v);
                    else
                        vTb[((size_t)(b * 12 + h) * 64 + d) * 1024 + nn] = f2bu(v);
                } else if (MODE == 2) {
                    const float v = acc[m][n][r] + bias[col];
                    // tanh-GELU (max err ~3e-4 vs exact erf form; bf16-noise)
                    const float u = 0.7978845608028654f * (v + 0.044715f * v * v * v);
                    const float th = 1.0f - 2.0f / (__expf(2.0f * u) + 1.0f);
                    Cb[(size_t)row * Ndim + col] = f2bu(0.5f * v * (1.0f + th));
                } else {
                    unsigned short* dst = Cb + (size_t)blockIdx.z * 4096 * Ndim;
                    dst[(size_t)row * Ndim + col] = f2bu(acc[m][n][r]);
                }
            }
        }
    }
}

// ---------------- MFMA banded attention (R5 structure + T2 swizzle) ----------------
__global__ void __launch_bounds__(256)
attn_mfma_kernel(const unsigned short* __restrict__ qb, const unsigned short* __restrict__ kb,
                 const unsigned short* __restrict__ vTb, const unsigned short* __restrict__ embpad,
                 unsigned short* __restrict__ ctx)
{
    __shared__ __attribute__((aligned(16))) char lds[58368];
    short* Qps = (short*)(lds);
    short* Qs = (short*)(lds);
    short* Stage = (short*)(lds + 8192);
    unsigned short* Spos = (unsigned short*)(lds + 24576);   // [64][264]
    short* PLall = (short*)(lds);                            // [4][16*320] swizzled
    short* Vt = (short*)(lds + 40960);                       // [64][64]

    const int i0 = blockIdx.x * 64;
    const int h = blockIdx.y, b = blockIdx.z;
    const int tid = threadIdx.x;
    const int l = tid & 63, w = tid >> 6;
    const int lm = l & 15, lg4 = l >> 4;
    const int l7 = l & 7;
    const int lrow = l >> 3;
    const int lcolsw = ((l & 7) ^ lrow) * 8;     // pre-swizzled source chunk
    const size_t bh = (size_t)(b * 12 + h);

    // ---- stage Qpos (scrambled rows), swizzled source ----
#pragma unroll
    for (int c = 0; c < 2; ++c) {
        const int row = w * 16 + c * 8 + lrow;
        const int iq = i0 + row;
        const int t2 = iq * 4 + b;
        const int b2 = t2 >> 10, n2 = t2 & 1023;
        const unsigned short* g = qb + ((size_t)(b2 * 12 + h) * 1024 + n2) * 64 + lcolsw;
        GLDS16(g, Qps + (w * 16 + c * 8) * 64);
    }
    __syncthreads();

    bf16x8 afp[2];
#pragma unroll
    for (int kk = 0; kk < 2; ++kk)
        afp[kk] = *(const bf16x8*)(Qps + (w * 16 + lm) * 64 + SWZ_OFF(kk * 4 + lg4, l7));

    // ---- phase 1: Spos = Qpos . Emb^T ----
#pragma unroll
    for (int et = 0; et < 4; ++et) {
        __syncthreads();
#pragma unroll
        for (int c = 0; c < 2; ++c) {
            const int row = w * 16 + c * 8 + lrow;
            const unsigned short* g = embpad + ((size_t)h * 256 + et * 64 + row) * 64 + lcolsw;
            GLDS16(g, Stage + (w * 16 + c * 8) * 64);
        }
        __syncthreads();
        f32x4 cp[4];
#pragma unroll
        for (int sub = 0; sub < 4; ++sub) cp[sub] = (f32x4){0.f, 0.f, 0.f, 0.f};
#pragma unroll
        for (int kk = 0; kk < 2; ++kk)
#pragma unroll
            for (int sub = 0; sub < 4; ++sub) {
                const bf16x8 bv = *(const bf16x8*)(Stage + (sub * 16 + lm) * 64 + SWZ_OFF(kk * 4 + lg4, l7));
                cp[sub] = __builtin_amdgcn_mfma_f32_16x16x32_bf16(afp[kk], bv, cp[sub], 0, 0, 0);
            }
#pragma unroll
        for (int sub = 0; sub < 4; ++sub)
#pragma unroll
            for (int r = 0; r < 4; ++r)
                Spos[(w * 16 + lg4 * 4 + r) * 264 + et * 64 + sub * 16 + lm] = f2bu(cp[sub][r]);
    }

    // ---- stage Q (straight rows) ----
#pragma unroll
    for (int c = 0; c < 2; ++c) {
        const int row = w * 16 + c * 8 + lrow;
        const unsigned short* g = qb + (bh * 1024 + i0 + row) * 64 + lcolsw;
        GLDS16(g, Qs + (w * 16 + c * 8) * 64);
    }

    const int jw0 = (i0 > 128) ? i0 - 128 : 0;
    const int hiex = (i0 + 163 < 1024) ? i0 + 163 : 1024;
    const int nt = (hiex - jw0 + 63) >> 6;

    f32x4 s[5][4];
#pragma unroll
    for (int ct = 0; ct < 5; ++ct)
#pragma unroll
        for (int sub = 0; sub < 4; ++sub) s[ct][sub] = (f32x4){0.f, 0.f, 0.f, 0.f};
    bf16x8 afq[2];

    // ---- phase 2: S = Q K^T ----
#pragma unroll
    for (int ct = 0; ct < 5; ++ct) {
        __syncthreads();
        if (ct < nt) {
#pragma unroll
            for (int c = 0; c < 2; ++c) {
                const int row = w * 16 + c * 8 + lrow;
                const unsigned short* g = kb + (bh * 1024 + jw0 + ct * 64 + row) * 64 + lcolsw;
                GLDS16(g, Stage + (w * 16 + c * 8) * 64);
            }
        }
        __syncthreads();
        if (ct == 0) {
#pragma unroll
            for (int kk = 0; kk < 2; ++kk)
                afq[kk] = *(const bf16x8*)(Qs + (w * 16 + lm) * 64 + SWZ_OFF(kk * 4 + lg4, l7));
        }
        if (ct < nt) {
#pragma unroll
            for (int kk = 0; kk < 2; ++kk)
#pragma unroll
                for (int sub = 0; sub < 4; ++sub) {
                    const bf16x8 bv = *(const bf16x8*)(Stage + (sub * 16 + lm) * 64 + SWZ_OFF(kk * 4 + lg4, l7));
                    s[ct][sub] = __builtin_amdgcn_mfma_f32_16x16x32_bf16(afq[kk], bv, s[ct][sub], 0, 0, 0);
                }
        }
    }

    // ---- combine + softmax ----
    const int irel = w * 16 + lg4 * 4;
    float mx[4] = {-1e30f, -1e30f, -1e30f, -1e30f};
#pragma unroll
    for (int ct = 0; ct < 5; ++ct)
#pragma unroll
        for (int sub = 0; sub < 4; ++sub)
#pragma unroll
            for (int r = 0; r < 4; ++r) {
                const int i = i0 + irel + r;
                const int j = jw0 + ct * 64 + sub * 16 + lm;
                const int rr = j - i + 99;
                const int rc = (rr < 0) ? 0 : (rr > 198 ? 198 : rr);
                const float ps = bu2f(Spos[(irel + r) * 264 + rc]);
                const bool ok = (ct < nt) && (rr >= 0) && (rr <= 198);
                const float lg = ok ? (0.125f * s[ct][sub][r] + ps) : -1e30f;
                s[ct][sub][r] = lg;
                mx[r] = fmaxf(mx[r], lg);
            }
#pragma unroll
    for (int m = 1; m < 16; m <<= 1)
#pragma unroll
        for (int r = 0; r < 4; ++r) mx[r] = fmaxf(mx[r], __shfl_xor(mx[r], m, 64));

    float sm[4] = {0.f, 0.f, 0.f, 0.f};
#pragma unroll
    for (int ct = 0; ct < 5; ++ct)
#pragma unroll
        for (int sub = 0; sub < 4; ++sub)
#pragma unroll
            for (int r = 0; r < 4; ++r) {
                const float p = __expf(s[ct][sub][r] - mx[r]);
                s[ct][sub][r] = p;
                sm[r] += p;
            }
#pragma unroll
    for (int m = 1; m < 16; m <<= 1)
#pragma unroll
        for (int r = 0; r < 4; ++r) sm[r] += __shfl_xor(sm[r], m, 64);
    float inv[4];
#pragma unroll
    for (int r = 0; r < 4; ++r) inv[r] = 1.0f / sm[r];

    __syncthreads();   // Spos reads done -> PL / Vt regions reusable

    // ---- P -> per-wave swizzled LDS (own XOR scheme, unchanged) ----
    short* PLw = PLall + w * 5120;
#pragma unroll
    for (int ct = 0; ct < 5; ++ct)
#pragma unroll
        for (int sub = 0; sub < 4; ++sub)
#pragma unroll
            for (int r = 0; r < 4; ++r) {
                const int rowrel = lg4 * 4 + r;
                const int colrel = ct * 64 + sub * 16 + lm;
                int byte = rowrel * 640 + colrel * 2;
                byte ^= ((rowrel & 7) << 4);
                *(short*)((char*)PLw + byte) = (short)f2bu(s[ct][sub][r] * inv[r]);
            }

    // ---- phase 3: O = P V ----
    f32x4 o[4];
#pragma unroll
    for (int sub = 0; sub < 4; ++sub) o[sub] = (f32x4){0.f, 0.f, 0.f, 0.f};
#pragma unroll
    for (int ct = 0; ct < 5; ++ct) {
        if (ct < nt) {
#pragma unroll
            for (int c = 0; c < 2; ++c) {
                const int dd = w * 16 + c * 8 + lrow;
                const unsigned short* g = vTb + (bh * 64 + dd) * 1024 + jw0 + ct * 64 + lcolsw;
                GLDS16(g, Vt + (w * 16 + c * 8) * 64);
            }
        }
        __syncthreads();
        if (ct < nt) {
#pragma unroll
            for (int kk = 0; kk < 2; ++kk) {
                const int colrel = ct * 64 + kk * 32 + lg4 * 8;
                int byte = lm * 640 + colrel * 2;
                byte ^= ((lm & 7) << 4);
                const bf16x8 ap = *(const bf16x8*)((char*)PLw + byte);
#pragma unroll
                for (int sub = 0; sub < 4; ++sub) {
                    const bf16x8 bv = *(const bf16x8*)(Vt + (sub * 16 + lm) * 64 + SWZ_OFF(kk * 4 + lg4, l7));
                    o[sub] = __builtin_amdgcn_mfma_f32_16x16x32_bf16(ap, bv, o[sub], 0, 0, 0);
                }
            }
        }
        __syncthreads();
    }

#pragma unroll
    for (int sub = 0; sub < 4; ++sub)
#pragma unroll
        for (int r = 0; r < 4; ++r) {
            const int i = i0 + w * 16 + lg4 * 4 + r;
            const int d = sub * 16 + lm;
            ctx[((size_t)b * 1024 + i) * 768 + h * 64 + d] = f2bu(o[sub][r]);
        }
}

// ---------------- fused split-K reduce + bias + residual + LayerNorm ----------------
__global__ void __launch_bounds__(256)
ln_fuse_kernel(const unsigned short* __restrict__ p0, const unsigned short* __restrict__ p1,
               const float* __restrict__ bias,
               const float* __restrict__ residf, const unsigned short* __restrict__ residb,
               const float* __restrict__ g, const float* __restrict__ bta,
               float* __restrict__ outf, unsigned short* __restrict__ outb)
{
    const int row = blockIdx.x;
    const int t = threadIdx.x;
    const size_t base = (size_t)row * 768;
    float v[3];
#pragma unroll
    for (int e = 0; e < 3; ++e) {
        const int idx = t + e * 256;
        const float r = residf ? residf[base + idx] : bu2f(residb[base + idx]);
        v[e] = bu2f(p0[base + idx]) + bu2f(p1[base + idx]) + bias[idx] + r;
    }
    __shared__ float red[4];
    float s = v[0] + v[1] + v[2];
#pragma unroll
    for (int off = 32; off > 0; off >>= 1) s += __shfl_down(s, off);
    if ((t & 63) == 0) red[t >> 6] = s;
    __syncthreads();
    const float mu = (red[0] + red[1] + red[2] + red[3]) * (1.0f / 768.0f);
    __syncthreads();
    const float d0 = v[0] - mu, d1 = v[1] - mu, d2 = v[2] - mu;
    float q = d0 * d0 + d1 * d1 + d2 * d2;
#pragma unroll
    for (int off = 32; off > 0; off >>= 1) q += __shfl_down(q, off);
    if ((t & 63) == 0) red[t >> 6] = q;
    __syncthreads();
    const float var = (red[0] + red[1] + red[2] + red[3]) * (1.0f / 768.0f);
    const float rstd = rsqrtf(var + 1e-5f);
    const float y0 = d0 * rstd * g[t] + bta[t];
    const float y1 = d1 * rstd * g[t + 256] + bta[t + 256];
    const float y2 = d2 * rstd * g[t + 512] + bta[t + 512];
    if (outf) { outf[base + t] = y0; outf[base + t + 256] = y1; outf[base + t + 512] = y2; }
    if (outb) { outb[base + t] = f2bu(y0); outb[base + t + 256] = f2bu(y1); outb[base + t + 512] = f2bu(y2); }
}

extern "C" void kernel_launch(void* const* d_in, const int* in_sizes, int n_in,
                              void* d_out, int out_size, void* d_ws, size_t ws_size,
                              hipStream_t stream)
{
    const float* src    = (const float*)d_in[0];
    const float* qkv_w  = (const float*)d_in[1];
    const float* qkv_b  = (const float*)d_in[2];
    const float* rel    = (const float*)d_in[3];
    const float* proj_w = (const float*)d_in[4];
    const float* proj_b = (const float*)d_in[5];
    const float* ln1_g  = (const float*)d_in[6];
    const float* ln1_b  = (const float*)d_in[7];
    const float* fc1_w  = (const float*)d_in[8];
    const float* fc1_b  = (const float*)d_in[9];
    const float* fc2_w  = (const float*)d_in[10];
    const float* fc2_b  = (const float*)d_in[11];
    const float* ln2_g  = (const float*)d_in[12];
    const float* ln2_b  = (const float*)d_in[13];
    float* out = (float*)d_out;
    char* W = (char*)d_ws;

    // Workspace layout (same as R8, peak 55050240 B = 52.5 MB).
    unsigned short* q_b     = (unsigned short*)(W + 0);
    unsigned short* k_b     = (unsigned short*)(W + 6291456);
    unsigned short* vT_b    = (unsigned short*)(W + 12582912);
    unsigned short* src_b   = (unsigned short*)(W + 18874368);
    unsigned short* ctx_b   = (unsigned short*)(W + 18874368);
    unsigned short* h1_b    = (unsigned short*)(W + 0);
    unsigned short* qkvw_b  = (unsigned short*)(W + 25165824);
    unsigned short* PP      = (unsigned short*)(W + 25165824);  // PP0 | PP1 (2 x 6291456 B)
    unsigned short* FP      = (unsigned short*)(W + 25165824);  // FP0 | FP1 (2 x 6291456 B)
    unsigned short* projw_b = (unsigned short*)(W + 37748736);
    unsigned short* fc1w_b  = (unsigned short*)(W + 38928384);
    unsigned short* fc2w_b  = (unsigned short*)(W + 43646976);
    unsigned short* embp_b  = (unsigned short*)(W + 48365568);
    unsigned short* xbuf_b  = (unsigned short*)(W + 48758784);

    // 0) converts
    convert_all_kernel<<<9984, 256, 0, stream>>>(
        src, qkv_w, proj_w, fc1_w, fc2_w, src_b, qkvw_b, projw_b, fc1w_b, fc2w_b);
    embpad_kernel<<<768, 256, 0, stream>>>(rel, embp_b);

    // 1) QKV: (4096x768)@(2304x768)^T -> scatter q/k/vT
    gemm64_kernel<0><<<dim3(36, 32, 1), 256, 0, stream>>>(
        src_b, qkvw_b, qkv_b, nullptr, 2304, 768, 768, q_b, k_b, vT_b);

    // 2) banded MFMA attention -> ctx bf16
    attn_mfma_kernel<<<dim3(16, 12, 4), 256, 0, stream>>>(q_b, k_b, vT_b, embp_b, ctx_b);

    // 3) proj, split-K x2 -> PP0/PP1 partials (bf16)
    gemm64_kernel<3><<<dim3(12, 32, 2), 256, 0, stream>>>(
        ctx_b, projw_b, nullptr, PP, 768, 768, 384, nullptr, nullptr, nullptr);

    // 4) LN1 = PP0+PP1+proj_b+src -> LN -> xbuf_b
    ln_fuse_kernel<<<4096, 256, 0, stream>>>(
        PP, PP + 4096 * 768, proj_b, src, nullptr, ln1_g, ln1_b, nullptr, xbuf_b);

    // 5) fc1 + bias + GELU -> h1 bf16
    gemm64_kernel<2><<<dim3(48, 32, 1), 256, 0, stream>>>(
        xbuf_b, fc1w_b, fc1_b, h1_b, 3072, 768, 768, nullptr, nullptr, nullptr);

    // 6) fc2, split-K x2 (K=3072 -> 2x1536) -> FP0/FP1
    gemm64_kernel<3><<<dim3(12, 32, 2), 256, 0, stream>>>(
        h1_b, fc2w_b, nullptr, FP, 768, 3072, 1536, nullptr, nullptr, nullptr);

    // 7) LN2 = FP0+FP1+fc2_b+xbuf_b -> LN -> out (f32)
    ln_fuse_kernel<<<4096, 256, 0, stream>>>(
        FP, FP + 4096 * 768, fc2_b, nullptr, xbuf_b, ln2_g, ln2_b, out, nullptr);
}

// Round 10
// 170.911 us; speedup vs baseline: 11.5100x; 1.0011x over previous
//
#include <hip/hip_runtime.h>
#include <hip/hip_bf16.h>
#include <math.h>

// B=4, N=1024, D=768, H=12, HD=64, M=100, FF=3072
// Attention EXACTLY banded radius 99. Round 10: T4 counted-vmcnt K-loop —
// raw s_barriers + explicit s_waitcnt vmcnt(6) so the t+1 prefetch (6
// global_load_lds per wave) stays in flight across barriers; T5 setprio
// around the MFMA cluster. Everything else frozen from R9.

typedef __attribute__((ext_vector_type(8))) short bf16x8;
typedef __attribute__((ext_vector_type(4))) float f32x4;

#define GLDS16(g, l) __builtin_amdgcn_global_load_lds( \
    (const __attribute__((address_space(1))) void*)(g), \
    (__attribute__((address_space(3))) void*)(l), 16, 0, 0)

__device__ __forceinline__ unsigned short f2bu(float x) {
    union { __hip_bfloat16 h; unsigned short u; } c;
    c.h = __float2bfloat16(x);
    return c.u;
}
__device__ __forceinline__ float bu2f(unsigned short u) {
    union { __hip_bfloat16 h; unsigned short u; } c;
    c.u = u;
    return __bfloat162float(c.h);
}

// ---------------- fused fp32 -> bf16 convert of all 5 tensors ----------------
__global__ void __launch_bounds__(256)
convert_all_kernel(const float* __restrict__ s0, const float* __restrict__ s1,
                   const float* __restrict__ s2, const float* __restrict__ s3,
                   const float* __restrict__ s4,
                   unsigned short* __restrict__ d0, unsigned short* __restrict__ d1,
                   unsigned short* __restrict__ d2, unsigned short* __restrict__ d3,
                   unsigned short* __restrict__ d4)
{
    const int idx = blockIdx.x * 256 + threadIdx.x;
    const float* s; unsigned short* d; int off;
    if (idx < 786432)       { s = s0; d = d0; off = idx; }
    else if (idx < 1228800) { s = s1; d = d1; off = idx - 786432; }
    else if (idx < 1376256) { s = s2; d = d2; off = idx - 1228800; }
    else if (idx < 1966080) { s = s3; d = d3; off = idx - 1376256; }
    else if (idx < 2555904) { s = s4; d = d4; off = idx - 1966080; }
    else return;
    const float4 v = ((const float4*)s)[off];
    ushort4 o;
    o.x = f2bu(v.x); o.y = f2bu(v.y); o.z = f2bu(v.z); o.w = f2bu(v.w);
    ((ushort4*)d)[off] = o;
}

// emb (H,199,HD,1) fp32 -> embpad (H,256,HD) bf16, rows r>=199 zeroed
__global__ void __launch_bounds__(256)
embpad_kernel(const float* __restrict__ rel, unsigned short* __restrict__ embpad)
{
    const int idx = blockIdx.x * 256 + threadIdx.x;
    if (idx >= 12 * 256 * 64) return;
    const int d = idx & 63;
    const int rp = (idx >> 6) & 255;
    const int h = idx >> 14;
    embpad[idx] = (rp < 199) ? f2bu(rel[((h * 199 + rp) << 6) + d]) : (unsigned short)0;
}

// Swizzle helper: LDS(row, c) holds global chunk c ^ (row&7); read chunk ch of
// row r at LDS chunk ch ^ (r&7). Chunks are 8 shorts = 16 B.
#define SWZ_OFF(ch, row7) ((((ch) ^ (row7)) * 8))

// ---------------- bf16 MFMA GEMM, NT, 128x64 tile, dbuf LDS, swizzled ----------------
// MODE 0: +bias, scatter q (b,h,n,d) / k (b,h,n,d) / vT (b,h,d,n) bf16
// MODE 2: +bias, tanh-GELU -> Cb bf16
// MODE 3: raw partial -> Cb + blockIdx.z*4096*Ndim elements (bf16)
template<int MODE>
__global__ void __launch_bounds__(256)
gemm64_kernel(const unsigned short* __restrict__ A, const unsigned short* __restrict__ Wt,
              const float* __restrict__ bias, unsigned short* __restrict__ Cb,
              int Ndim, int K, int Ksplit,
              unsigned short* __restrict__ qb, unsigned short* __restrict__ kb,
              unsigned short* __restrict__ vTb)
{
    __shared__ short As[2 * 128 * 64];   // 2 x 16 KB
    __shared__ short Bs[2 * 64 * 64];    // 2 x 8 KB
    const int tid = threadIdx.x;
    const int l = tid & 63;
    const int w = tid >> 6;
    const int wr = w >> 1, wc = w & 1;

    // XCD-aware swizzle of flattened xy (nxy % 8 == 0 for all our grids)
    int flat = blockIdx.y * gridDim.x + blockIdx.x;
    const int nxy = gridDim.x * gridDim.y;
    flat = (flat & 7) * (nxy >> 3) + (flat >> 3);
    const int bx = flat % gridDim.x;
    const int by = flat / gridDim.x;

    const int row0 = by * 128;
    const int col0 = bx * 64;
    const int koff = blockIdx.z * Ksplit;
    const int nt = Ksplit >> 6;

    const int lrow = l >> 3;                      // 0..7
    const int lcol = ((l & 7) ^ lrow) * 8;        // PRE-SWIZZLED source chunk
    const int l7 = l & 7;

    f32x4 acc[4][2];
#pragma unroll
    for (int m = 0; m < 4; ++m)
#pragma unroll
        for (int n = 0; n < 2; ++n) acc[m][n] = (f32x4){0.f, 0.f, 0.f, 0.f};

    // stage K-tile t into buffer buf: 6 global_load_lds per wave
#define STAGE(buf, t) do {                                                        \
    const int k0 = koff + (t) * 64;                                               \
    _Pragma("unroll")                                                             \
    for (int it = 0; it < 4; ++it) {                                              \
        const int c = w * 4 + it;                                                 \
        GLDS16(A + (size_t)(row0 + c * 8 + lrow) * K + k0 + lcol,                 \
               As + (buf) * 8192 + c * 512);                                      \
    }                                                                             \
    _Pragma("unroll")                                                             \
    for (int it = 0; it < 2; ++it) {                                              \
        const int c = w * 2 + it;                                                 \
        GLDS16(Wt + (size_t)(col0 + c * 8 + lrow) * K + k0 + lcol,                \
               Bs + (buf) * 4096 + c * 512);                                      \
    }                                                                             \
} while (0)

    STAGE(0, 0);

    for (int t = 0; t < nt; ++t) {
        const int buf = t & 1;
        // T4: issue next tile, then wait only for THIS tile (vmcnt(6) leaves
        // the 6 just-issued prefetch loads in flight across both barriers).
        if (t + 1 < nt) {
            STAGE(buf ^ 1, t + 1);
            asm volatile("s_waitcnt vmcnt(6)" ::: "memory");
        } else {
            asm volatile("s_waitcnt vmcnt(0)" ::: "memory");
        }
        __builtin_amdgcn_sched_barrier(0);
        __builtin_amdgcn_s_barrier();            // all waves: tile t staged

        const short* a = As + buf * 8192;
        const short* bsp = Bs + buf * 4096;
        __builtin_amdgcn_s_setprio(1);           // T5
#pragma unroll
        for (int kk = 0; kk < 2; ++kk) {
            const int ch = kk * 4 + (l >> 4);     // logical 16B chunk 0..7
            bf16x8 af[4], bfr[2];
#pragma unroll
            for (int m = 0; m < 4; ++m)
                af[m] = *(const bf16x8*)(a + (wr * 64 + m * 16 + (l & 15)) * 64 + SWZ_OFF(ch, l7));
#pragma unroll
            for (int n = 0; n < 2; ++n)
                bfr[n] = *(const bf16x8*)(bsp + (wc * 32 + n * 16 + (l & 15)) * 64 + SWZ_OFF(ch, l7));
#pragma unroll
            for (int m = 0; m < 4; ++m)
#pragma unroll
                for (int n = 0; n < 2; ++n)
                    acc[m][n] = __builtin_amdgcn_mfma_f32_16x16x32_bf16(af[m], bfr[n], acc[m][n], 0, 0, 0);
        }
        __builtin_amdgcn_s_setprio(0);
        if (t + 1 < nt)
            __builtin_amdgcn_s_barrier();        // reads of buf done -> t+2 may overwrite
    }
#undef STAGE

    // Epilogue. D map: col = lane&15, row = (lane>>4)*4 + reg
#pragma unroll
    for (int m = 0; m < 4; ++m) {
#pragma unroll
        for (int n = 0; n < 2; ++n) {
#pragma unroll
            for (int r = 0; r < 4; ++r) {
                const int row = row0 + wr * 64 + m * 16 + (l >> 4) * 4 + r;
                const int col = col0 + wc * 32 + n * 16 + (l & 15);
                if (MODE == 0) {
                    const float v = acc[m][n][r] + bias[col];
                    const int which = col / 768;
                    const int rem = col - which * 768;
                    const int h = rem >> 6, d = rem & 63;
                    const int b = row >> 10, nn = row & 1023;
                    if (which == 0)
                        qb[((size_t)(b * 12 + h) * 1024 + nn) * 64 + d] = f2bu(v);
                    else if (which == 1)
                        kb[((size_t)(b * 12 + h) * 1024 + nn) * 64 + d] = f2bu(v);
                    else
                        vTb[((size_t)(b * 12 + h) * 64 + d) * 1024 + nn] = f2bu(v);
                } else if (MODE == 2) {
                    const float v = acc[m][n][r] + bias[col];
                    const float u = 0.7978845608028654f * (v + 0.044715f * v * v * v);
                    const float th = 1.0f - 2.0f / (__expf(2.0f * u) + 1.0f);
                    Cb[(size_t)row * Ndim + col] = f2bu(0.5f * v * (1.0f + th));
                } else {
                    unsigned short* dst = Cb + (size_t)blockIdx.z * 4096 * Ndim;
                    dst[(size_t)row * Ndim + col] = f2bu(acc[m][n][r]);
                }
            }
        }
    }
}

// ---------------- MFMA banded attention (R9, frozen) ----------------
__global__ void __launch_bounds__(256)
attn_mfma_kernel(const unsigned short* __restrict__ qb, const unsigned short* __restrict__ kb,
                 const unsigned short* __restrict__ vTb, const unsigned short* __restrict__ embpad,
                 unsigned short* __restrict__ ctx)
{
    __shared__ __attribute__((aligned(16))) char lds[58368];
    short* Qps = (short*)(lds);
    short* Qs = (short*)(lds);
    short* Stage = (short*)(lds + 8192);
    unsigned short* Spos = (unsigned short*)(lds + 24576);   // [64][264]
    short* PLall = (short*)(lds);                            // [4][16*320] swizzled
    short* Vt = (short*)(lds + 40960);                       // [64][64]

    const int i0 = blockIdx.x * 64;
    const int h = blockIdx.y, b = blockIdx.z;
    const int tid = threadIdx.x;
    const int l = tid & 63, w = tid >> 6;
    const int lm = l & 15, lg4 = l >> 4;
    const int l7 = l & 7;
    const int lrow = l >> 3;
    const int lcolsw = ((l & 7) ^ lrow) * 8;
    const size_t bh = (size_t)(b * 12 + h);

#pragma unroll
    for (int c = 0; c < 2; ++c) {
        const int row = w * 16 + c * 8 + lrow;
        const int iq = i0 + row;
        const int t2 = iq * 4 + b;
        const int b2 = t2 >> 10, n2 = t2 & 1023;
        const unsigned short* g = qb + ((size_t)(b2 * 12 + h) * 1024 + n2) * 64 + lcolsw;
        GLDS16(g, Qps + (w * 16 + c * 8) * 64);
    }
    __syncthreads();

    bf16x8 afp[2];
#pragma unroll
    for (int kk = 0; kk < 2; ++kk)
        afp[kk] = *(const bf16x8*)(Qps + (w * 16 + lm) * 64 + SWZ_OFF(kk * 4 + lg4, l7));

#pragma unroll
    for (int et = 0; et < 4; ++et) {
        __syncthreads();
#pragma unroll
        for (int c = 0; c < 2; ++c) {
            const int row = w * 16 + c * 8 + lrow;
            const unsigned short* g = embpad + ((size_t)h * 256 + et * 64 + row) * 64 + lcolsw;
            GLDS16(g, Stage + (w * 16 + c * 8) * 64);
        }
        __syncthreads();
        f32x4 cp[4];
#pragma unroll
        for (int sub = 0; sub < 4; ++sub) cp[sub] = (f32x4){0.f, 0.f, 0.f, 0.f};
#pragma unroll
        for (int kk = 0; kk < 2; ++kk)
#pragma unroll
            for (int sub = 0; sub < 4; ++sub) {
                const bf16x8 bv = *(const bf16x8*)(Stage + (sub * 16 + lm) * 64 + SWZ_OFF(kk * 4 + lg4, l7));
                cp[sub] = __builtin_amdgcn_mfma_f32_16x16x32_bf16(afp[kk], bv, cp[sub], 0, 0, 0);
            }
#pragma unroll
        for (int sub = 0; sub < 4; ++sub)
#pragma unroll
            for (int r = 0; r < 4; ++r)
                Spos[(w * 16 + lg4 * 4 + r) * 264 + et * 64 + sub * 16 + lm] = f2bu(cp[sub][r]);
    }

#pragma unroll
    for (int c = 0; c < 2; ++c) {
        const int row = w * 16 + c * 8 + lrow;
        const unsigned short* g = qb + (bh * 1024 + i0 + row) * 64 + lcolsw;
        GLDS16(g, Qs + (w * 16 + c * 8) * 64);
    }

    const int jw0 = (i0 > 128) ? i0 - 128 : 0;
    const int hiex = (i0 + 163 < 1024) ? i0 + 163 : 1024;
    const int nt = (hiex - jw0 + 63) >> 6;

    f32x4 s[5][4];
#pragma unroll
    for (int ct = 0; ct < 5; ++ct)
#pragma unroll
        for (int sub = 0; sub < 4; ++sub) s[ct][sub] = (f32x4){0.f, 0.f, 0.f, 0.f};
    bf16x8 afq[2];

#pragma unroll
    for (int ct = 0; ct < 5; ++ct) {
        __syncthreads();
        if (ct < nt) {
#pragma unroll
            for (int c = 0; c < 2; ++c) {
                const int row = w * 16 + c * 8 + lrow;
                const unsigned short* g = kb + (bh * 1024 + jw0 + ct * 64 + row) * 64 + lcolsw;
                GLDS16(g, Stage + (w * 16 + c * 8) * 64);
            }
        }
        __syncthreads();
        if (ct == 0) {
#pragma unroll
            for (int kk = 0; kk < 2; ++kk)
                afq[kk] = *(const bf16x8*)(Qs + (w * 16 + lm) * 64 + SWZ_OFF(kk * 4 + lg4, l7));
        }
        if (ct < nt) {
#pragma unroll
            for (int kk = 0; kk < 2; ++kk)
#pragma unroll
                for (int sub = 0; sub < 4; ++sub) {
                    const bf16x8 bv = *(const bf16x8*)(Stage + (sub * 16 + lm) * 64 + SWZ_OFF(kk * 4 + lg4, l7));
                    s[ct][sub] = __builtin_amdgcn_mfma_f32_16x16x32_bf16(afq[kk], bv, s[ct][sub], 0, 0, 0);
                }
        }
    }

    const int irel = w * 16 + lg4 * 4;
    float mx[4] = {-1e30f, -1e30f, -1e30f, -1e30f};
#pragma unroll
    for (int ct = 0; ct < 5; ++ct)
#pragma unroll
        for (int sub = 0; sub < 4; ++sub)
#pragma unroll
            for (int r = 0; r < 4; ++r) {
                const int i = i0 + irel + r;
                const int j = jw0 + ct * 64 + sub * 16 + lm;
                const int rr = j - i + 99;
                const int rc = (rr < 0) ? 0 : (rr > 198 ? 198 : rr);
                const float ps = bu2f(Spos[(irel + r) * 264 + rc]);
                const bool ok = (ct < nt) && (rr >= 0) && (rr <= 198);
                const float lg = ok ? (0.125f * s[ct][sub][r] + ps) : -1e30f;
                s[ct][sub][r] = lg;
                mx[r] = fmaxf(mx[r], lg);
            }
#pragma unroll
    for (int m = 1; m < 16; m <<= 1)
#pragma unroll
        for (int r = 0; r < 4; ++r) mx[r] = fmaxf(mx[r], __shfl_xor(mx[r], m, 64));

    float sm[4] = {0.f, 0.f, 0.f, 0.f};
#pragma unroll
    for (int ct = 0; ct < 5; ++ct)
#pragma unroll
        for (int sub = 0; sub < 4; ++sub)
#pragma unroll
            for (int r = 0; r < 4; ++r) {
                const float p = __expf(s[ct][sub][r] - mx[r]);
                s[ct][sub][r] = p;
                sm[r] += p;
            }
#pragma unroll
    for (int m = 1; m < 16; m <<= 1)
#pragma unroll
        for (int r = 0; r < 4; ++r) sm[r] += __shfl_xor(sm[r], m, 64);
    float inv[4];
#pragma unroll
    for (int r = 0; r < 4; ++r) inv[r] = 1.0f / sm[r];

    __syncthreads();

    short* PLw = PLall + w * 5120;
#pragma unroll
    for (int ct = 0; ct < 5; ++ct)
#pragma unroll
        for (int sub = 0; sub < 4; ++sub)
#pragma unroll
            for (int r = 0; r < 4; ++r) {
                const int rowrel = lg4 * 4 + r;
                const int colrel = ct * 64 + sub * 16 + lm;
                int byte = rowrel * 640 + colrel * 2;
                byte ^= ((rowrel & 7) << 4);
                *(short*)((char*)PLw + byte) = (short)f2bu(s[ct][sub][r] * inv[r]);
            }

    f32x4 o[4];
#pragma unroll
    for (int sub = 0; sub < 4; ++sub) o[sub] = (f32x4){0.f, 0.f, 0.f, 0.f};
#pragma unroll
    for (int ct = 0; ct < 5; ++ct) {
        if (ct < nt) {
#pragma unroll
            for (int c = 0; c < 2; ++c) {
                const int dd = w * 16 + c * 8 + lrow;
                const unsigned short* g = vTb + (bh * 64 + dd) * 1024 + jw0 + ct * 64 + lcolsw;
                GLDS16(g, Vt + (w * 16 + c * 8) * 64);
            }
        }
        __syncthreads();
        if (ct < nt) {
#pragma unroll
            for (int kk = 0; kk < 2; ++kk) {
                const int colrel = ct * 64 + kk * 32 + lg4 * 8;
                int byte = lm * 640 + colrel * 2;
                byte ^= ((lm & 7) << 4);
                const bf16x8 ap = *(const bf16x8*)((char*)PLw + byte);
#pragma unroll
                for (int sub = 0; sub < 4; ++sub) {
                    const bf16x8 bv = *(const bf16x8*)(Vt + (sub * 16 + lm) * 64 + SWZ_OFF(kk * 4 + lg4, l7));
                    o[sub] = __builtin_amdgcn_mfma_f32_16x16x32_bf16(ap, bv, o[sub], 0, 0, 0);
                }
            }
        }
        __syncthreads();
    }

#pragma unroll
    for (int sub = 0; sub < 4; ++sub)
#pragma unroll
        for (int r = 0; r < 4; ++r) {
            const int i = i0 + w * 16 + lg4 * 4 + r;
            const int d = sub * 16 + lm;
            ctx[((size_t)b * 1024 + i) * 768 + h * 64 + d] = f2bu(o[sub][r]);
        }
}

// ---------------- fused split-K reduce + bias + residual + LayerNorm ----------------
__global__ void __launch_bounds__(256)
ln_fuse_kernel(const unsigned short* __restrict__ p0, const unsigned short* __restrict__ p1,
               const float* __restrict__ bias,
               const float* __restrict__ residf, const unsigned short* __restrict__ residb,
               const float* __restrict__ g, const float* __restrict__ bta,
               float* __restrict__ outf, unsigned short* __restrict__ outb)
{
    const int row = blockIdx.x;
    const int t = threadIdx.x;
    const size_t base = (size_t)row * 768;
    float v[3];
#pragma unroll
    for (int e = 0; e < 3; ++e) {
        const int idx = t + e * 256;
        const float r = residf ? residf[base + idx] : bu2f(residb[base + idx]);
        v[e] = bu2f(p0[base + idx]) + bu2f(p1[base + idx]) + bias[idx] + r;
    }
    __shared__ float red[4];
    float s = v[0] + v[1] + v[2];
#pragma unroll
    for (int off = 32; off > 0; off >>= 1) s += __shfl_down(s, off);
    if ((t & 63) == 0) red[t >> 6] = s;
    __syncthreads();
    const float mu = (red[0] + red[1] + red[2] + red[3]) * (1.0f / 768.0f);
    __syncthreads();
    const float d0 = v[0] - mu, d1 = v[1] - mu, d2 = v[2] - mu;
    float q = d0 * d0 + d1 * d1 + d2 * d2;
#pragma unroll
    for (int off = 32; off > 0; off >>= 1) q += __shfl_down(q, off);
    if ((t & 63) == 0) red[t >> 6] = q;
    __syncthreads();
    const float var = (red[0] + red[1] + red[2] + red[3]) * (1.0f / 768.0f);
    const float rstd = rsqrtf(var + 1e-5f);
    const float y0 = d0 * rstd * g[t] + bta[t];
    const float y1 = d1 * rstd * g[t + 256] + bta[t + 256];
    const float y2 = d2 * rstd * g[t + 512] + bta[t + 512];
    if (outf) { outf[base + t] = y0; outf[base + t + 256] = y1; outf[base + t + 512] = y2; }
    if (outb) { outb[base + t] = f2bu(y0); outb[base + t + 256] = f2bu(y1); outb[base + t + 512] = f2bu(y2); }
}

extern "C" void kernel_launch(void* const* d_in, const int* in_sizes, int n_in,
                              void* d_out, int out_size, void* d_ws, size_t ws_size,
                              hipStream_t stream)
{
    const float* src    = (const float*)d_in[0];
    const float* qkv_w  = (const float*)d_in[1];
    const float* qkv_b  = (const float*)d_in[2];
    const float* rel    = (const float*)d_in[3];
    const float* proj_w = (const float*)d_in[4];
    const float* proj_b = (const float*)d_in[5];
    const float* ln1_g  = (const float*)d_in[6];
    const float* ln1_b  = (const float*)d_in[7];
    const float* fc1_w  = (const float*)d_in[8];
    const float* fc1_b  = (const float*)d_in[9];
    const float* fc2_w  = (const float*)d_in[10];
    const float* fc2_b  = (const float*)d_in[11];
    const float* ln2_g  = (const float*)d_in[12];
    const float* ln2_b  = (const float*)d_in[13];
    float* out = (float*)d_out;
    char* W = (char*)d_ws;

    // Workspace layout (same as R8/R9, peak 55050240 B = 52.5 MB).
    unsigned short* q_b     = (unsigned short*)(W + 0);
    unsigned short* k_b     = (unsigned short*)(W + 6291456);
    unsigned short* vT_b    = (unsigned short*)(W + 12582912);
    unsigned short* src_b   = (unsigned short*)(W + 18874368);
    unsigned short* ctx_b   = (unsigned short*)(W + 18874368);
    unsigned short* h1_b    = (unsigned short*)(W + 0);
    unsigned short* qkvw_b  = (unsigned short*)(W + 25165824);
    unsigned short* PP      = (unsigned short*)(W + 25165824);  // PP0 | PP1 (2 x 6291456 B)
    unsigned short* FP      = (unsigned short*)(W + 25165824);  // FP0 | FP1 (2 x 6291456 B)
    unsigned short* projw_b = (unsigned short*)(W + 37748736);
    unsigned short* fc1w_b  = (unsigned short*)(W + 38928384);
    unsigned short* fc2w_b  = (unsigned short*)(W + 43646976);
    unsigned short* embp_b  = (unsigned short*)(W + 48365568);
    unsigned short* xbuf_b  = (unsigned short*)(W + 48758784);

    // 0) converts
    convert_all_kernel<<<9984, 256, 0, stream>>>(
        src, qkv_w, proj_w, fc1_w, fc2_w, src_b, qkvw_b, projw_b, fc1w_b, fc2w_b);
    embpad_kernel<<<768, 256, 0, stream>>>(rel, embp_b);

    // 1) QKV: (4096x768)@(2304x768)^T -> scatter q/k/vT
    gemm64_kernel<0><<<dim3(36, 32, 1), 256, 0, stream>>>(
        src_b, qkvw_b, qkv_b, nullptr, 2304, 768, 768, q_b, k_b, vT_b);

    // 2) banded MFMA attention -> ctx bf16
    attn_mfma_kernel<<<dim3(16, 12, 4), 256, 0, stream>>>(q_b, k_b, vT_b, embp_b, ctx_b);

    // 3) proj, split-K x2 -> PP0/PP1 partials (bf16)
    gemm64_kernel<3><<<dim3(12, 32, 2), 256, 0, stream>>>(
        ctx_b, projw_b, nullptr, PP, 768, 768, 384, nullptr, nullptr, nullptr);

    // 4) LN1 = PP0+PP1+proj_b+src -> LN -> xbuf_b
    ln_fuse_kernel<<<4096, 256, 0, stream>>>(
        PP, PP + 4096 * 768, proj_b, src, nullptr, ln1_g, ln1_b, nullptr, xbuf_b);

    // 5) fc1 + bias + GELU -> h1 bf16
    gemm64_kernel<2><<<dim3(48, 32, 1), 256, 0, stream>>>(
        xbuf_b, fc1w_b, fc1_b, h1_b, 3072, 768, 768, nullptr, nullptr, nullptr);

    // 6) fc2, split-K x2 (K=3072 -> 2x1536) -> FP0/FP1
    gemm64_kernel<3><<<dim3(12, 32, 2), 256, 0, stream>>>(
        h1_b, fc2w_b, nullptr, FP, 768, 3072, 1536, nullptr, nullptr, nullptr);

    // 7) LN2 = FP0+FP1+fc2_b+xbuf_b -> LN -> out (f32)
    ln_fuse_kernel<<<4096, 256, 0, stream>>>(
        FP, FP + 4096 * 768, fc2_b, nullptr, xbuf_b, ln2_g, ln2_b, out, nullptr);
}